// Round 2
// baseline (437.532 us; speedup 1.0000x reference)
//
#include <hip/hip_runtime.h>

#define NROWS   131072
#define DIM     64
#define K       1024
#define QOFF    1
#define IDXOFF  8388609        // 1 + NROWS*DIM
// Routing margin in 2^-20 distance units (~4.0e-4). Hard error bound of the
// fp16 screen is 2^-19 * sum|x_i| per distance; sound for sum|x_i| <= 104.8
// (11-sigma for chi-64 rows, P ~ 1e-23 across all rows), + 2 for trunc quant.
#define MQ      422

typedef float    f32x4 __attribute__((ext_vector_type(4)));
typedef _Float16 f16x8 __attribute__((ext_vector_type(8)));

// ---------- np-exact arithmetic (validated: absmax 0.0) ----------
__device__ __forceinline__ float np_norm64(const float* v) {
    #pragma clang fp contract(off)
    float r[8];
    #pragma unroll
    for (int k = 0; k < 8; ++k) r[k] = v[k] * v[k];
    #pragma unroll
    for (int i = 8; i < 64; i += 8)
        #pragma unroll
        for (int k = 0; k < 8; ++k) r[k] += v[i + k] * v[i + k];
    return ((r[0] + r[1]) + (r[2] + r[3])) + ((r[4] + r[5]) + (r[6] + r[7]));
}
__device__ __forceinline__ float exact_dot64(const float* xr, const float* __restrict__ e) {
    float a0 = 0.f, a1 = 0.f, a2 = 0.f, a3 = 0.f;
    #pragma unroll
    for (int i = 0; i < 64; i += 4) {
        a0 = fmaf(xr[i + 0], e[i + 0], a0);
        a1 = fmaf(xr[i + 1], e[i + 1], a1);
        a2 = fmaf(xr[i + 2], e[i + 2], a2);
        a3 = fmaf(xr[i + 3], e[i + 3], a3);
    }
    return (a0 + a1) + (a2 + a3);
}
__device__ __forceinline__ float exact_d(float cr, float sej, float dot) {
    #pragma clang fp contract(off)
    float t = cr + sej;
    return t - 2.0f * dot;
}

// ---------- prep: W -> fp16(1024*e) + np-exact se (+ se*2^20 for the screen) ----------
__global__ void vq_prep(const float* __restrict__ w, unsigned short* __restrict__ Gh,
                        float* __restrict__ se, float* __restrict__ se20) {
    int gid = blockIdx.x * 256 + threadIdx.x;       // 0..8191
    int n = gid >> 3, s = gid & 7;
    const float* row = w + n * 64 + s * 8;
    f16x8 h8;
    #pragma unroll
    for (int j = 0; j < 8; ++j) h8[j] = (_Float16)(row[j] * 1024.0f);   // *1024 exact; RNE to fp16
    *(f16x8*)(Gh + n * 64 + s * 8) = h8;
    if (gid < K) {
        #pragma clang fp contract(off)
        const float* e = w + gid * 64;
        float r[8];
        #pragma unroll
        for (int k2 = 0; k2 < 8; ++k2) r[k2] = e[k2] * e[k2];
        #pragma unroll
        for (int i = 8; i < 64; i += 8)
            #pragma unroll
            for (int k2 = 0; k2 < 8; ++k2) r[k2] += e[i + k2] * e[i + k2];
        float v = ((r[0] + r[1]) + (r[2] + r[3])) + ((r[4] + r[5]) + (r[6] + r[7]));
        se[gid] = v;
        se20[gid] = v * 1048576.0f;                 // exact (power of 2)
    }
}

// ---------- screen: single fp16 MFMA product + packed-int top-3 ----------
// block = 256 (4 waves); wave = 32 rows (2 M-tiles); block = 128 rows; grid = 1024.
// key = (trunc(f*2^20) << 10) | j  — monotone in f, ties broken toward lower index (np rule).
__global__ __launch_bounds__(256, 4) void vq_screen(
    const float* __restrict__ x, const float* __restrict__ w,
    const unsigned short* __restrict__ Gh, const float* __restrict__ se20,
    float* __restrict__ out,
    int* __restrict__ counters, int* __restrict__ pairList, int* __restrict__ fullList) {
    __shared__ f32x4 sB[1024];          // 16 KB: 128-code fp16 chunk, bank-swizzled
    __shared__ float sSe[1024];         // 4 KB:  se*2^20, staged once
    __shared__ int jrow[128];
    const int tid  = threadIdx.x;
    const int wave = tid >> 6, lane = tid & 63;
    const int quad = lane >> 4, m16 = lane & 15;
    const int rowBlk = blockIdx.x * 128;
    const int wrow0  = rowBlk + wave * 32;

    // stage all se20 once (read via LDS in the hot loop — no global load stalls)
    #pragma unroll
    for (int t = 0; t < 4; ++t) sSe[t * 256 + tid] = se20[t * 256 + tid];

    // A fragments: fp16(x), layout A[m = lane&15][k = quad*8 + j], chunk c: k = 32c..32c+31
    f16x8 Ah[2][2];
    #pragma unroll
    for (int mt = 0; mt < 2; ++mt)
        #pragma unroll
        for (int c = 0; c < 2; ++c) {
            const float* p = x + (wrow0 + mt * 16 + m16) * 64 + c * 32 + quad * 8;
            f32x4 u0 = *(const f32x4*)p;
            f32x4 u1 = *(const f32x4*)(p + 4);
            #pragma unroll
            for (int j = 0; j < 8; ++j)
                Ah[mt][c][j] = (_Float16)((j < 4) ? u0[j] : u1[j - 4]);
        }

    int m1[2][4], m2[2][4], m3[2][4];
    #pragma unroll
    for (int mt = 0; mt < 2; ++mt)
        #pragma unroll
        for (int r = 0; r < 4; ++r) {
            m1[mt][r] = 0x7fffffff; m2[mt][r] = 0x7fffffff; m3[mt][r] = 0x7fffffff;
        }

    // software-pipelined staging: prefetch chunk 0 into regs
    const int n0 = tid >> 3, s0 = tid & 7;
    f32x4 pre[4];
    #pragma unroll
    for (int it = 0; it < 4; ++it)
        pre[it] = *(const f32x4*)(Gh + (it * 32 + n0) * 64 + s0 * 8);

    for (int ch = 0; ch < 8; ++ch) {
        __syncthreads();
        #pragma unroll
        for (int it = 0; it < 4; ++it) {
            int n = it * 32 + n0;
            sB[n * 8 + ((s0 + (n & 7)) & 7)] = pre[it];     // swizzled placement
        }
        __syncthreads();
        if (ch < 7) {                                       // issue next chunk's loads early;
            #pragma unroll                                  // vmcnt wait hides under nt-loop
            for (int it = 0; it < 4; ++it) {
                int n = it * 32 + n0;
                pre[it] = *(const f32x4*)(Gh + ((ch + 1) * 128 + n) * 64 + s0 * 8);
            }
        }

        #pragma unroll 2
        for (int nt = 0; nt < 8; ++nt) {
            int nl = nt * 16 + m16, swz = nl & 7;
            f16x8 B0 = __builtin_bit_cast(f16x8, sB[nl * 8 + ((quad + swz) & 7)]);
            f16x8 B1 = __builtin_bit_cast(f16x8, sB[nl * 8 + ((4 + quad + swz) & 7)]);
            float sen = sSe[ch * 128 + nl];
            int jn = ch * 128 + nl;
            #pragma unroll
            for (int mt = 0; mt < 2; ++mt) {
                f32x4 acc = {0.f, 0.f, 0.f, 0.f};
                acc = __builtin_amdgcn_mfma_f32_16x16x32_f16(Ah[mt][0], B0, acc, 0, 0, 0);
                acc = __builtin_amdgcn_mfma_f32_16x16x32_f16(Ah[mt][1], B1, acc, 0, 0, 0);
                #pragma unroll
                for (int r = 0; r < 4; ++r) {
                    // f*2^20 = se*2^20 - 2*2^-10*2^20*dot' ; dot' = 1024*x.e
                    float kf = fmaf(acc[r], -2048.0f, sen);
                    int q = (int)kf;                              // trunc: monotone
                    int key = (int)((unsigned)q << 10) | jn;
                    int a  = max(m2[mt][r], key);                 // old m2
                    int t2 = max(m1[mt][r], key);                 // old m1
                    m3[mt][r] = min(m3[mt][r], a);
                    m2[mt][r] = min(m2[mt][r], t2);
                    m1[mt][r] = min(m1[mt][r], key);
                }
            }
        }
    }

    // cross-lane top-3 merge over the 16 cols of each row (C layout: col=lane&15, row=quad*4+r)
    #pragma unroll
    for (int mask = 1; mask <= 8; mask <<= 1) {
        #pragma unroll
        for (int mt = 0; mt < 2; ++mt)
            #pragma unroll
            for (int r = 0; r < 4; ++r) {
                int b1 = __shfl_xor(m1[mt][r], mask, 64);
                int b2 = __shfl_xor(m2[mt][r], mask, 64);
                int b3 = __shfl_xor(m3[mt][r], mask, 64);
                int lo1 = min(m1[mt][r], b1), hi1 = max(m1[mt][r], b1);
                int lo2 = min(m2[mt][r], b2);
                m1[mt][r] = lo1;
                m2[mt][r] = min(hi1, lo2);
                m3[mt][r] = min(max(hi1, lo2), min(m3[mt][r], b3));
            }
    }

    if (m16 == 0) {
        #pragma unroll
        for (int mt = 0; mt < 2; ++mt)
            #pragma unroll
            for (int r = 0; r < 4; ++r) {
                int rowL = wave * 32 + mt * 16 + quad * 4 + r;
                int rowG = rowBlk + rowL;
                int k1 = m1[mt][r], k2 = m2[mt][r], k3 = m3[mt][r];
                int g21 = (k2 >> 10) - (k1 >> 10);
                int g31 = (k3 >> 10) - (k1 >> 10);
                int j1 = k1 & 1023;
                if (g21 > MQ) {                               // provably unique winner
                    out[IDXOFF + rowG] = (float)j1;
                    jrow[rowL] = j1;
                } else {
                    jrow[rowL] = -1;
                    if (g31 > MQ) {                           // winner in {j1, j2}
                        int c = atomicAdd(&counters[0], 1);
                        pairList[3 * c] = rowG; pairList[3 * c + 1] = j1; pairList[3 * c + 2] = k2 & 1023;
                    } else {                                  // rare: full rescan
                        int c = atomicAdd(&counters[1], 1);
                        fullList[c] = rowG;
                    }
                }
            }
    }
    __syncthreads();

    // q_st + loss for decided rows, coalesced: lane = dim, one row at a time
    float part = 0.f;
    for (int i = 0; i < 32; ++i) {
        int jr = jrow[wave * 32 + i];      // wave-uniform
        if (jr < 0) continue;
        int rowG = wrow0 + i;
        {
            #pragma clang fp contract(off)
            float xv = x[rowG * 64 + lane];
            float wv = w[jr * 64 + lane];
            float diff = wv - xv;
            part += diff * diff;
            out[QOFF + rowG * 64 + lane] = xv + diff;
        }
    }
    for (int off = 32; off > 0; off >>= 1) part += __shfl_down(part, off, 64);
    if (lane == 0) atomicAdd(out, part * (1.25f / 8388608.0f));
}

// ---------- finish: exact pair-compares (per thread) + full rescans (per wave) ----------
__global__ __launch_bounds__(256) void vq_finish(
    const float* __restrict__ x, const float* __restrict__ w, const float* __restrict__ se,
    float* __restrict__ out, const int* __restrict__ counters,
    const int* __restrict__ pairList, const int* __restrict__ fullList) {
    const int tid = threadIdx.x;
    const int lane = tid & 63, wave = tid >> 6;
    const int nPair = counters[0], nFull = counters[1];
    const int gthread = blockIdx.x * 256 + tid, nThreads = gridDim.x * 256;
    const int gwave = blockIdx.x * 4 + wave,   nWaves = gridDim.x * 4;
    float part = 0.f;

    // Phase A: winner in {ja, jb}; exact compare with np first-index tie rule
    for (int i = gthread; i < nPair; i += nThreads) {
        int row = pairList[3 * i], ja = pairList[3 * i + 1], jb = pairList[3 * i + 2];
        if (ja > jb) { int t = ja; ja = jb; jb = t; }
        float xr[64];
        const f32x4* xp = (const f32x4*)(x + row * 64);
        #pragma unroll
        for (int t = 0; t < 16; ++t) {
            f32x4 v = xp[t];
            xr[4 * t] = v[0]; xr[4 * t + 1] = v[1]; xr[4 * t + 2] = v[2]; xr[4 * t + 3] = v[3];
        }
        float cr = np_norm64(xr);
        float da = exact_d(cr, se[ja], exact_dot64(xr, w + ja * 64));
        float db = exact_d(cr, se[jb], exact_dot64(xr, w + jb * 64));
        int win = (db < da) ? jb : ja;
        out[IDXOFF + row] = (float)win;
        const float* e = w + win * 64;
        {
            #pragma clang fp contract(off)
            #pragma unroll
            for (int i2 = 0; i2 < 64; ++i2) {
                float diff = e[i2] - xr[i2];
                part += diff * diff;
                out[QOFF + row * 64 + i2] = xr[i2] + diff;
            }
        }
    }

    // Phase B: full exact rescan, one row per wave (16 codes per lane)
    for (int i = gwave; i < nFull; i += nWaves) {
        int row = fullList[i];
        float xr[64];
        const f32x4* xp = (const f32x4*)(x + row * 64);
        #pragma unroll
        for (int t = 0; t < 16; ++t) {
            f32x4 v = xp[t];
            xr[4 * t] = v[0]; xr[4 * t + 1] = v[1]; xr[4 * t + 2] = v[2]; xr[4 * t + 3] = v[3];
        }
        float cr = np_norm64(xr);
        float bd = 3.402823466e38f; int bj = 0;
        for (int t = 0; t < 16; ++t) {
            int j = lane * 16 + t;
            float d = exact_d(cr, se[j], exact_dot64(xr, w + j * 64));
            if (d < bd) { bd = d; bj = j; }
        }
        for (int mask = 1; mask < 64; mask <<= 1) {
            float od = __shfl_xor(bd, mask, 64);
            int   oj = __shfl_xor(bj, mask, 64);
            if (od < bd || (od == bd && oj < bj)) { bd = od; bj = oj; }
        }
        {
            #pragma clang fp contract(off)
            float xv = x[row * 64 + lane];
            float wv = w[bj * 64 + lane];
            float diff = wv - xv;
            part += diff * diff;
            out[QOFF + row * 64 + lane] = xv + diff;
        }
        if (lane == 0) out[IDXOFF + row] = (float)bj;
    }

    for (int off = 32; off > 0; off >>= 1) part += __shfl_down(part, off, 64);
    if (lane == 0 && part != 0.f) atomicAdd(out, part * (1.25f / 8388608.0f));
}

extern "C" void kernel_launch(void* const* d_in, const int* in_sizes, int n_in,
                              void* d_out, int out_size, void* d_ws, size_t ws_size,
                              hipStream_t stream) {
    const float* x = (const float*)d_in[0];
    const float* w = (const float*)d_in[1];
    float* out = (float*)d_out;

    unsigned short* Gh = (unsigned short*)d_ws;                  // 128 KB fp16(1024*e)
    float* se   = (float*)((char*)d_ws + 131072);                // 4 KB
    float* se20 = (float*)((char*)d_ws + 135168);                // 4 KB
    int* counters = (int*)((char*)d_ws + 139264);                // 8 B
    int* pairList = (int*)((char*)d_ws + 139272);                // <= 1.5 MB
    int* fullList = pairList + 3 * NROWS;                        // <= 512 KB

    (void)hipMemsetAsync(out, 0, sizeof(float), stream);         // loss accumulator
    (void)hipMemsetAsync(counters, 0, 2 * sizeof(int), stream);
    vq_prep<<<32, 256, 0, stream>>>(w, Gh, se, se20);
    vq_screen<<<1024, 256, 0, stream>>>(x, w, Gh, se20, out, counters, pairList, fullList);
    vq_finish<<<256, 256, 0, stream>>>(x, w, se, out, counters, pairList, fullList);
}

// Round 3
// 403.261 us; speedup vs baseline: 1.0850x; 1.0850x over previous
//
#include <hip/hip_runtime.h>

#define NROWS   131072
#define DIM     64
#define K       1024
#define QOFF    1
#define IDXOFF  8388609        // 1 + NROWS*DIM
// Routing margin in 2^-20 distance units (~4.0e-4). Hard error bound of the
// fp16 screen is 2^-19 * sum|x_i| per distance; sound for sum|x_i| <= 104.8
// (11-sigma for chi-64 rows, P ~ 1e-23 across all rows), + 2 for trunc quant.
#define MQ      422
#define NPART   1024           // screen grid
#define NFIN    256            // finish grid

typedef float    f32x4 __attribute__((ext_vector_type(4)));
typedef _Float16 f16x8 __attribute__((ext_vector_type(8)));

// ---------- np-exact arithmetic (validated: absmax 0.0) ----------
__device__ __forceinline__ float np_norm64(const float* v) {
    #pragma clang fp contract(off)
    float r[8];
    #pragma unroll
    for (int k = 0; k < 8; ++k) r[k] = v[k] * v[k];
    #pragma unroll
    for (int i = 8; i < 64; i += 8)
        #pragma unroll
        for (int k = 0; k < 8; ++k) r[k] += v[i + k] * v[i + k];
    return ((r[0] + r[1]) + (r[2] + r[3])) + ((r[4] + r[5]) + (r[6] + r[7]));
}
__device__ __forceinline__ float exact_dot64(const float* xr, const float* __restrict__ e) {
    float a0 = 0.f, a1 = 0.f, a2 = 0.f, a3 = 0.f;
    #pragma unroll
    for (int i = 0; i < 64; i += 4) {
        a0 = fmaf(xr[i + 0], e[i + 0], a0);
        a1 = fmaf(xr[i + 1], e[i + 1], a1);
        a2 = fmaf(xr[i + 2], e[i + 2], a2);
        a3 = fmaf(xr[i + 3], e[i + 3], a3);
    }
    return (a0 + a1) + (a2 + a3);
}
__device__ __forceinline__ float exact_d(float cr, float sej, float dot) {
    #pragma clang fp contract(off)
    float t = cr + sej;
    return t - 2.0f * dot;
}

// ---------- prep: W -> fp16(1024*e) + np-exact se (+ se*2^20 for the screen) ----------
__global__ void vq_prep(const float* __restrict__ w, unsigned short* __restrict__ Gh,
                        float* __restrict__ se, float* __restrict__ se20) {
    int gid = blockIdx.x * 256 + threadIdx.x;       // 0..8191
    int n = gid >> 3, s = gid & 7;
    const float* row = w + n * 64 + s * 8;
    f16x8 h8;
    #pragma unroll
    for (int j = 0; j < 8; ++j) h8[j] = (_Float16)(row[j] * 1024.0f);   // *1024 exact; RNE to fp16
    *(f16x8*)(Gh + n * 64 + s * 8) = h8;
    if (gid < K) {
        #pragma clang fp contract(off)
        const float* e = w + gid * 64;
        float r[8];
        #pragma unroll
        for (int k2 = 0; k2 < 8; ++k2) r[k2] = e[k2] * e[k2];
        #pragma unroll
        for (int i = 8; i < 64; i += 8)
            #pragma unroll
            for (int k2 = 0; k2 < 8; ++k2) r[k2] += e[i + k2] * e[i + k2];
        float v = ((r[0] + r[1]) + (r[2] + r[3])) + ((r[4] + r[5]) + (r[6] + r[7]));
        se[gid] = v;
        se20[gid] = v * 1048576.0f;                 // exact (power of 2)
    }
}

// ---------- screen: single fp16 MFMA product + packed-int top-3 ----------
// block = 256 (4 waves); wave = 32 rows (2 M-tiles); block = 128 rows; grid = 1024.
// key = (trunc(f*2^20) << 10) | j  — monotone in f, ties broken toward lower index (np rule).
// NO same-address atomics: per-block loss partial -> partial[blockIdx].
__global__ __launch_bounds__(256, 4) void vq_screen(
    const float* __restrict__ x, const float* __restrict__ w,
    const unsigned short* __restrict__ Gh, const float* __restrict__ se20,
    float* __restrict__ out, float* __restrict__ partial,
    int* __restrict__ counters, int* __restrict__ pairList, int* __restrict__ fullList) {
    __shared__ f32x4 sB[1024];          // 16 KB: 128-code fp16 chunk, bank-swizzled
    __shared__ float sSe[1024];         // 4 KB:  se*2^20, staged once
    __shared__ int jrow[128];
    __shared__ float sPart[4];
    const int tid  = threadIdx.x;
    const int wave = tid >> 6, lane = tid & 63;
    const int quad = lane >> 4, m16 = lane & 15;
    const int rowBlk = blockIdx.x * 128;
    const int wrow0  = rowBlk + wave * 32;

    // stage all se20 once (read via LDS in the hot loop — no global load stalls)
    #pragma unroll
    for (int t = 0; t < 4; ++t) sSe[t * 256 + tid] = se20[t * 256 + tid];

    // A fragments: fp16(x), layout A[m = lane&15][k = quad*8 + j], chunk c: k = 32c..32c+31
    f16x8 Ah[2][2];
    #pragma unroll
    for (int mt = 0; mt < 2; ++mt)
        #pragma unroll
        for (int c = 0; c < 2; ++c) {
            const float* p = x + (wrow0 + mt * 16 + m16) * 64 + c * 32 + quad * 8;
            f32x4 u0 = *(const f32x4*)p;
            f32x4 u1 = *(const f32x4*)(p + 4);
            #pragma unroll
            for (int j = 0; j < 8; ++j)
                Ah[mt][c][j] = (_Float16)((j < 4) ? u0[j] : u1[j - 4]);
        }

    int m1[2][4], m2[2][4], m3[2][4];
    #pragma unroll
    for (int mt = 0; mt < 2; ++mt)
        #pragma unroll
        for (int r = 0; r < 4; ++r) {
            m1[mt][r] = 0x7fffffff; m2[mt][r] = 0x7fffffff; m3[mt][r] = 0x7fffffff;
        }

    // software-pipelined staging: prefetch chunk 0 into regs
    const int n0 = tid >> 3, s0 = tid & 7;
    f32x4 pre[4];
    #pragma unroll
    for (int it = 0; it < 4; ++it)
        pre[it] = *(const f32x4*)(Gh + (it * 32 + n0) * 64 + s0 * 8);

    for (int ch = 0; ch < 8; ++ch) {
        __syncthreads();
        #pragma unroll
        for (int it = 0; it < 4; ++it) {
            int n = it * 32 + n0;
            sB[n * 8 + ((s0 + (n & 7)) & 7)] = pre[it];     // swizzled placement
        }
        __syncthreads();
        if (ch < 7) {                                       // issue next chunk's loads early;
            #pragma unroll                                  // vmcnt wait hides under nt-loop
            for (int it = 0; it < 4; ++it) {
                int n = it * 32 + n0;
                pre[it] = *(const f32x4*)(Gh + ((ch + 1) * 128 + n) * 64 + s0 * 8);
            }
        }

        #pragma unroll
        for (int nt = 0; nt < 8; ++nt) {
            int nl = nt * 16 + m16, swz = nl & 7;
            f16x8 B0 = __builtin_bit_cast(f16x8, sB[nl * 8 + ((quad + swz) & 7)]);
            f16x8 B1 = __builtin_bit_cast(f16x8, sB[nl * 8 + ((4 + quad + swz) & 7)]);
            float sen = sSe[ch * 128 + nl];
            int jn = ch * 128 + nl;
            #pragma unroll
            for (int mt = 0; mt < 2; ++mt) {
                f32x4 acc = {0.f, 0.f, 0.f, 0.f};
                acc = __builtin_amdgcn_mfma_f32_16x16x32_f16(Ah[mt][0], B0, acc, 0, 0, 0);
                acc = __builtin_amdgcn_mfma_f32_16x16x32_f16(Ah[mt][1], B1, acc, 0, 0, 0);
                #pragma unroll
                for (int r = 0; r < 4; ++r) {
                    // f*2^20 = se*2^20 - 2*2^-10*2^20*dot' ; dot' = 1024*x.e
                    float kf = fmaf(acc[r], -2048.0f, sen);
                    int q = (int)kf;                              // trunc: monotone
                    int key = (int)((unsigned)q << 10) | jn;
                    int a  = max(m2[mt][r], key);                 // old m2
                    int t2 = max(m1[mt][r], key);                 // old m1
                    m3[mt][r] = min(m3[mt][r], a);
                    m2[mt][r] = min(m2[mt][r], t2);
                    m1[mt][r] = min(m1[mt][r], key);
                }
            }
        }
    }

    // cross-lane top-3 merge over the 16 cols of each row (C layout: col=lane&15, row=quad*4+r)
    #pragma unroll
    for (int mask = 1; mask <= 8; mask <<= 1) {
        #pragma unroll
        for (int mt = 0; mt < 2; ++mt)
            #pragma unroll
            for (int r = 0; r < 4; ++r) {
                int b1 = __shfl_xor(m1[mt][r], mask, 64);
                int b2 = __shfl_xor(m2[mt][r], mask, 64);
                int b3 = __shfl_xor(m3[mt][r], mask, 64);
                int lo1 = min(m1[mt][r], b1), hi1 = max(m1[mt][r], b1);
                int lo2 = min(m2[mt][r], b2);
                m1[mt][r] = lo1;
                m2[mt][r] = min(hi1, lo2);
                m3[mt][r] = min(max(hi1, lo2), min(m3[mt][r], b3));
            }
    }

    if (m16 == 0) {
        #pragma unroll
        for (int mt = 0; mt < 2; ++mt)
            #pragma unroll
            for (int r = 0; r < 4; ++r) {
                int rowL = wave * 32 + mt * 16 + quad * 4 + r;
                int rowG = rowBlk + rowL;
                int k1 = m1[mt][r], k2 = m2[mt][r], k3 = m3[mt][r];
                int g21 = (k2 >> 10) - (k1 >> 10);
                int g31 = (k3 >> 10) - (k1 >> 10);
                int j1 = k1 & 1023;
                if (g21 > MQ) {                               // provably unique winner
                    out[IDXOFF + rowG] = (float)j1;
                    jrow[rowL] = j1;
                } else {
                    jrow[rowL] = -1;
                    if (g31 > MQ) {                           // winner in {j1, j2}
                        int c = atomicAdd(&counters[0], 1);
                        pairList[3 * c] = rowG; pairList[3 * c + 1] = j1; pairList[3 * c + 2] = k2 & 1023;
                    } else {                                  // rare: full rescan
                        int c = atomicAdd(&counters[1], 1);
                        fullList[c] = rowG;
                    }
                }
            }
    }
    __syncthreads();

    // q_st + loss for decided rows, coalesced: lane = dim, one row at a time
    float part = 0.f;
    for (int i = 0; i < 32; ++i) {
        int jr = jrow[wave * 32 + i];      // wave-uniform
        if (jr < 0) continue;
        int rowG = wrow0 + i;
        {
            #pragma clang fp contract(off)
            float xv = x[rowG * 64 + lane];
            float wv = w[jr * 64 + lane];
            float diff = wv - xv;
            part += diff * diff;
            out[QOFF + rowG * 64 + lane] = xv + diff;
        }
    }
    for (int off = 32; off > 0; off >>= 1) part += __shfl_down(part, off, 64);
    if (lane == 0) sPart[wave] = part;
    __syncthreads();
    if (tid == 0) partial[blockIdx.x] = (sPart[0] + sPart[1]) + (sPart[2] + sPart[3]);
}

// ---------- finish: exact pair-compares (per thread) + full rescans (per wave) ----------
__global__ __launch_bounds__(256) void vq_finish(
    const float* __restrict__ x, const float* __restrict__ w, const float* __restrict__ se,
    float* __restrict__ out, float* __restrict__ partial, const int* __restrict__ counters,
    const int* __restrict__ pairList, const int* __restrict__ fullList) {
    __shared__ float sPart[4];
    const int tid = threadIdx.x;
    const int lane = tid & 63, wave = tid >> 6;
    const int nPair = counters[0], nFull = counters[1];
    const int gthread = blockIdx.x * 256 + tid, nThreads = gridDim.x * 256;
    const int gwave = blockIdx.x * 4 + wave,   nWaves = gridDim.x * 4;
    float part = 0.f;

    // Phase A: winner in {ja, jb}; exact compare with np first-index tie rule
    for (int i = gthread; i < nPair; i += nThreads) {
        int row = pairList[3 * i], ja = pairList[3 * i + 1], jb = pairList[3 * i + 2];
        if (ja > jb) { int t = ja; ja = jb; jb = t; }
        float xr[64];
        const f32x4* xp = (const f32x4*)(x + row * 64);
        #pragma unroll
        for (int t = 0; t < 16; ++t) {
            f32x4 v = xp[t];
            xr[4 * t] = v[0]; xr[4 * t + 1] = v[1]; xr[4 * t + 2] = v[2]; xr[4 * t + 3] = v[3];
        }
        float cr = np_norm64(xr);
        float da = exact_d(cr, se[ja], exact_dot64(xr, w + ja * 64));
        float db = exact_d(cr, se[jb], exact_dot64(xr, w + jb * 64));
        int win = (db < da) ? jb : ja;
        out[IDXOFF + row] = (float)win;
        const float* e = w + win * 64;
        {
            #pragma clang fp contract(off)
            #pragma unroll
            for (int i2 = 0; i2 < 64; ++i2) {
                float diff = e[i2] - xr[i2];
                part += diff * diff;
                out[QOFF + row * 64 + i2] = xr[i2] + diff;
            }
        }
    }

    // Phase B: full exact rescan, one row per wave (16 codes per lane)
    for (int i = gwave; i < nFull; i += nWaves) {
        int row = fullList[i];
        float xr[64];
        const f32x4* xp = (const f32x4*)(x + row * 64);
        #pragma unroll
        for (int t = 0; t < 16; ++t) {
            f32x4 v = xp[t];
            xr[4 * t] = v[0]; xr[4 * t + 1] = v[1]; xr[4 * t + 2] = v[2]; xr[4 * t + 3] = v[3];
        }
        float cr = np_norm64(xr);
        float bd = 3.402823466e38f; int bj = 0;
        for (int t = 0; t < 16; ++t) {
            int j = lane * 16 + t;
            float d = exact_d(cr, se[j], exact_dot64(xr, w + j * 64));
            if (d < bd) { bd = d; bj = j; }
        }
        for (int mask = 1; mask < 64; mask <<= 1) {
            float od = __shfl_xor(bd, mask, 64);
            int   oj = __shfl_xor(bj, mask, 64);
            if (od < bd || (od == bd && oj < bj)) { bd = od; bj = oj; }
        }
        {
            #pragma clang fp contract(off)
            float xv = x[row * 64 + lane];
            float wv = w[bj * 64 + lane];
            float diff = wv - xv;
            part += diff * diff;
            out[QOFF + row * 64 + lane] = xv + diff;
        }
        if (lane == 0) out[IDXOFF + row] = (float)bj;
    }

    for (int off = 32; off > 0; off >>= 1) part += __shfl_down(part, off, 64);
    if (lane == 0) sPart[wave] = part;
    __syncthreads();
    if (tid == 0) partial[NPART + blockIdx.x] = (sPart[0] + sPart[1]) + (sPart[2] + sPart[3]);
}

// ---------- loss: single block sums the 1280 per-block partials, one writer ----------
__global__ __launch_bounds__(256) void vq_loss(const float* __restrict__ partial,
                                               float* __restrict__ out) {
    __shared__ float red[4];
    const int tid = threadIdx.x, lane = tid & 63, wave = tid >> 6;
    float s = 0.f;
    #pragma unroll
    for (int t = 0; t < 5; ++t) s += partial[t * 256 + tid];   // 5*256 = 1280 = NPART+NFIN
    for (int off = 32; off > 0; off >>= 1) s += __shfl_down(s, off, 64);
    if (lane == 0) red[wave] = s;
    __syncthreads();
    if (tid == 0) out[0] = ((red[0] + red[1]) + (red[2] + red[3])) * (1.25f / 8388608.0f);
}

extern "C" void kernel_launch(void* const* d_in, const int* in_sizes, int n_in,
                              void* d_out, int out_size, void* d_ws, size_t ws_size,
                              hipStream_t stream) {
    const float* x = (const float*)d_in[0];
    const float* w = (const float*)d_in[1];
    float* out = (float*)d_out;

    unsigned short* Gh = (unsigned short*)d_ws;                  // 128 KB fp16(1024*e)
    float* se   = (float*)((char*)d_ws + 131072);                // 4 KB
    float* se20 = (float*)((char*)d_ws + 135168);                // 4 KB
    int* counters = (int*)((char*)d_ws + 139264);                // 8 B
    int* pairList = (int*)((char*)d_ws + 139272);                // <= 1.5 MB
    int* fullList = pairList + 3 * NROWS;                        // <= 512 KB
    float* partial = (float*)(fullList + NROWS);                 // 5 KB (1280 floats)

    (void)hipMemsetAsync(out, 0, sizeof(float), stream);         // loss slot (vq_loss overwrites)
    (void)hipMemsetAsync(counters, 0, 2 * sizeof(int), stream);
    vq_prep<<<32, 256, 0, stream>>>(w, Gh, se, se20);
    vq_screen<<<NPART, 256, 0, stream>>>(x, w, Gh, se20, out, partial, counters, pairList, fullList);
    vq_finish<<<NFIN, 256, 0, stream>>>(x, w, se, out, partial, counters, pairList, fullList);
    vq_loss<<<1, 256, 0, stream>>>(partial, out);
}

// Round 5
// 298.381 us; speedup vs baseline: 1.4664x; 1.3515x over previous
//
#include <hip/hip_runtime.h>

#define NROWS   131072
#define DIM     64
#define K       1024
#define QOFF    1
#define IDXOFF  8388609        // 1 + NROWS*DIM
// Routing margin in 2^-20 distance units (~4.0e-4). Hard error bound of the
// fp16 screen is 2^-19 * sum|x_i| per distance; sound for sum|x_i| <= 104.8
// (11-sigma for chi-64 rows, P ~ 1e-23 across all rows), + 2 for trunc quant.
#define MQ      422
#define NSCR    2048           // screen grid (64 rows/block, 8 blocks/CU)
#define NFIN    256            // finish grid

typedef float    f32x4 __attribute__((ext_vector_type(4)));
typedef _Float16 f16x8 __attribute__((ext_vector_type(8)));

// ---------- np-exact arithmetic (validated: absmax 0.0) ----------
__device__ __forceinline__ float np_norm64(const float* v) {
    #pragma clang fp contract(off)
    float r[8];
    #pragma unroll
    for (int k = 0; k < 8; ++k) r[k] = v[k] * v[k];
    #pragma unroll
    for (int i = 8; i < 64; i += 8)
        #pragma unroll
        for (int k = 0; k < 8; ++k) r[k] += v[i + k] * v[i + k];
    return ((r[0] + r[1]) + (r[2] + r[3])) + ((r[4] + r[5]) + (r[6] + r[7]));
}
__device__ __forceinline__ float exact_dot64(const float* xr, const float* __restrict__ e) {
    float a0 = 0.f, a1 = 0.f, a2 = 0.f, a3 = 0.f;
    #pragma unroll
    for (int i = 0; i < 64; i += 4) {
        a0 = fmaf(xr[i + 0], e[i + 0], a0);
        a1 = fmaf(xr[i + 1], e[i + 1], a1);
        a2 = fmaf(xr[i + 2], e[i + 2], a2);
        a3 = fmaf(xr[i + 3], e[i + 3], a3);
    }
    return (a0 + a1) + (a2 + a3);
}
__device__ __forceinline__ float exact_d(float cr, float sej, float dot) {
    #pragma clang fp contract(off)
    float t = cr + sej;
    return t - 2.0f * dot;
}

// ---------- prep: W -> fp16(1024*e) in MFMA B-FRAGMENT ORDER + np-exact se ----------
// Gf layout: [ntile(64)][chunk(2)][lane(64)][8 halves].  Lane (quad,m16) of B-chunk c
// holds codes n = ntile*16+m16, k = c*32 + quad*8 + j  — exactly the 16x16x32 B fragment.
__global__ void vq_prep(const float* __restrict__ w, unsigned short* __restrict__ Gf,
                        float* __restrict__ se, float* __restrict__ se20) {
    int gid = blockIdx.x * 256 + threadIdx.x;       // 0..8191 = ntile*128 + c*64 + lane
    int lane = gid & 63, c = (gid >> 6) & 1, ntile = gid >> 7;
    int code = ntile * 16 + (lane & 15);
    int k0 = c * 32 + (lane >> 4) * 8;
    const float* rowp = w + code * 64 + k0;
    f16x8 h8;
    #pragma unroll
    for (int j = 0; j < 8; ++j) h8[j] = (_Float16)(rowp[j] * 1024.0f);  // *1024 exact; RNE
    *(f16x8*)(Gf + gid * 8) = h8;                    // fully coalesced 16B store
    if (gid < K) {
        #pragma clang fp contract(off)
        const float* e = w + gid * 64;
        float r[8];
        #pragma unroll
        for (int k2 = 0; k2 < 8; ++k2) r[k2] = e[k2] * e[k2];
        #pragma unroll
        for (int i = 8; i < 64; i += 8)
            #pragma unroll
            for (int k2 = 0; k2 < 8; ++k2) r[k2] += e[i + k2] * e[i + k2];
        float v = ((r[0] + r[1]) + (r[2] + r[3])) + ((r[4] + r[5]) + (r[6] + r[7]));
        se[gid] = v;
        se20[gid] = v * 1048576.0f;                 // exact (power of 2)
    }
}

// ---------- screen: barrierless fp16 MFMA scan + packed-int top-3, flag output ----------
// block = 256 (4 waves); ONE 16-row m-tile per wave; grid = 2048 (8 blocks/CU, ~full occ).
// B fragments come straight from Gf with coalesced 16B/lane loads (L2-resident, no LDS, no
// barriers, no staging).  flags[row]: -1 decided, -2 full-rescan, else j1 | (j2<<10).
__global__ __launch_bounds__(256, 8) void vq_screen(
    const float* __restrict__ x, const float* __restrict__ w,
    const unsigned short* __restrict__ Gf, const float* __restrict__ se20,
    float* __restrict__ out, float* __restrict__ partial, int* __restrict__ flags) {
    __shared__ float sSe[1024];         // 4 KB: se*2^20
    __shared__ float sPart[4];
    const int tid  = threadIdx.x;
    const int wave = tid >> 6, lane = tid & 63;
    const int quad = lane >> 4, m16 = lane & 15;
    const int wrow0 = blockIdx.x * 64 + wave * 16;

    #pragma unroll
    for (int t = 0; t < 4; ++t) sSe[t * 256 + tid] = se20[t * 256 + tid];

    // A fragment: fp16(x), A[m = m16][k = quad*8 + j], chunk c: k = 32c..32c+31
    f16x8 Ah[2];
    #pragma unroll
    for (int c = 0; c < 2; ++c) {
        const float* p = x + (wrow0 + m16) * 64 + c * 32 + quad * 8;
        f32x4 u0 = *(const f32x4*)p;
        f32x4 u1 = *(const f32x4*)(p + 4);
        #pragma unroll
        for (int j = 0; j < 8; ++j)
            Ah[c][j] = (_Float16)((j < 4) ? u0[j] : u1[j - 4]);
    }

    int m1[4], m2[4], m3[4];
    #pragma unroll
    for (int r = 0; r < 4; ++r) { m1[r] = 0x7fffffff; m2[r] = 0x7fffffff; m3[r] = 0x7fffffff; }

    __syncthreads();                    // sSe ready (the only block barrier before epilogue)

    #pragma unroll 4
    for (int t = 0; t < 64; ++t) {      // 64 code-tiles of 16
        f16x8 B0 = *(const f16x8*)(Gf + t * 1024 + lane * 8);        // chunk 0, coalesced
        f16x8 B1 = *(const f16x8*)(Gf + t * 1024 + 512 + lane * 8);  // chunk 1
        float sen = sSe[t * 16 + m16];
        int jn = t * 16 + m16;
        f32x4 acc = {0.f, 0.f, 0.f, 0.f};
        acc = __builtin_amdgcn_mfma_f32_16x16x32_f16(Ah[0], B0, acc, 0, 0, 0);
        acc = __builtin_amdgcn_mfma_f32_16x16x32_f16(Ah[1], B1, acc, 0, 0, 0);
        #pragma unroll
        for (int r = 0; r < 4; ++r) {
            // f*2^20 = se*2^20 - 2*2^-10*2^20*dot' ; dot' = 1024*x.e
            float kf = fmaf(acc[r], -2048.0f, sen);
            int q = (int)kf;                              // trunc: monotone
            int key = (int)((unsigned)q << 10) | jn;
            int a  = max(m2[r], key);                     // old m2
            int t2 = max(m1[r], key);                     // old m1
            m3[r] = min(m3[r], a);
            m2[r] = min(m2[r], t2);
            m1[r] = min(m1[r], key);
        }
    }

    // butterfly all-reduce top-3 over the 16 cols (C layout: col=m16, row=quad*4+r);
    // after the full butterfly EVERY lane holds the merged result for rows quad*4+r.
    #pragma unroll
    for (int mask = 1; mask <= 8; mask <<= 1) {
        #pragma unroll
        for (int r = 0; r < 4; ++r) {
            int b1 = __shfl_xor(m1[r], mask, 64);
            int b2 = __shfl_xor(m2[r], mask, 64);
            int b3 = __shfl_xor(m3[r], mask, 64);
            int lo1 = min(m1[r], b1), hi1 = max(m1[r], b1);
            int lo2 = min(m2[r], b2);
            m1[r] = lo1;
            m2[r] = min(hi1, lo2);
            m3[r] = min(max(hi1, lo2), min(m3[r], b3));
        }
    }

    int jd[4];                          // decided winner (or -1) for row quad*4+r, quad-uniform
    #pragma unroll
    for (int r = 0; r < 4; ++r) {
        int k1 = m1[r], k2 = m2[r], k3 = m3[r];
        int g21 = (k2 >> 10) - (k1 >> 10);
        int g31 = (k3 >> 10) - (k1 >> 10);
        int j1 = k1 & 1023;
        jd[r] = (g21 > MQ) ? j1 : -1;
        if (m16 == 0) {
            int rowG = wrow0 + quad * 4 + r;
            if (g21 > MQ) {
                out[IDXOFF + rowG] = (float)j1;
                flags[rowG] = -1;                          // decided here
            } else if (g31 > MQ) {
                flags[rowG] = j1 | ((k2 & 1023) << 10);    // winner in {j1, j2}
            } else {
                flags[rowG] = -2;                          // rare: full rescan
            }
        }
    }

    // q_st + loss for decided rows, coalesced: lane = dim; winner broadcast via static shfl
    float part = 0.f;
    #pragma unroll
    for (int i = 0; i < 16; ++i) {                         // row i = quad(i>>2)*4 + r(i&3)
        int jr = __shfl(jd[i & 3], (i >> 2) * 16, 64);
        if (jr >= 0) {
            #pragma clang fp contract(off)
            int rowG = wrow0 + i;
            float xv = x[rowG * 64 + lane];
            float wv = w[jr * 64 + lane];
            float diff = wv - xv;
            part += diff * diff;
            out[QOFF + rowG * 64 + lane] = xv + diff;
        }
    }
    for (int off = 32; off > 0; off >>= 1) part += __shfl_down(part, off, 64);
    if (lane == 0) sPart[wave] = part;
    __syncthreads();
    if (tid == 0) partial[blockIdx.x] = (sPart[0] + sPart[1]) + (sPart[2] + sPart[3]);
}

// ---------- finish: flag-scan; exact pair-compares (thread) + full rescans (wave) ----------
__global__ __launch_bounds__(256) void vq_finish(
    const float* __restrict__ x, const float* __restrict__ w, const float* __restrict__ se,
    float* __restrict__ out, float* __restrict__ partial, const int* __restrict__ flags) {
    __shared__ float sPart[4];
    const int tid = threadIdx.x;
    const int lane = tid & 63, wave = tid >> 6;
    const int gthread = blockIdx.x * 256 + tid, nThreads = gridDim.x * 256;
    const int gwave = blockIdx.x * 4 + wave,   nWaves = gridDim.x * 4;
    float part = 0.f;

    // Phase A: pair rows (flag >= 0); exact compare with np first-index tie rule
    for (int row = gthread; row < NROWS; row += nThreads) {
        int f = flags[row];
        if (f < 0) continue;
        int ja = f & 1023, jb = (f >> 10) & 1023;
        if (ja > jb) { int t = ja; ja = jb; jb = t; }
        float xr[64];
        const f32x4* xp = (const f32x4*)(x + row * 64);
        #pragma unroll
        for (int t = 0; t < 16; ++t) {
            f32x4 v = xp[t];
            xr[4 * t] = v[0]; xr[4 * t + 1] = v[1]; xr[4 * t + 2] = v[2]; xr[4 * t + 3] = v[3];
        }
        float cr = np_norm64(xr);
        float da = exact_d(cr, se[ja], exact_dot64(xr, w + ja * 64));
        float db = exact_d(cr, se[jb], exact_dot64(xr, w + jb * 64));
        int win = (db < da) ? jb : ja;
        out[IDXOFF + row] = (float)win;
        const float* e = w + win * 64;
        {
            #pragma clang fp contract(off)
            #pragma unroll
            for (int i2 = 0; i2 < 64; ++i2) {
                float diff = e[i2] - xr[i2];
                part += diff * diff;
                out[QOFF + row * 64 + i2] = xr[i2] + diff;
            }
        }
    }

    // Phase B: full rescans (flag == -2), wave-cooperative, found via ballot over windows
    for (int w0 = gwave * 64; w0 < NROWS; w0 += nWaves * 64) {
        int f = flags[w0 + lane];
        unsigned long long bm = __ballot(f == -2);
        while (bm) {
            int b = __ffsll((unsigned long long)bm) - 1;
            bm &= bm - 1;
            int row = w0 + b;
            float xr[64];
            const f32x4* xp = (const f32x4*)(x + row * 64);
            #pragma unroll
            for (int t = 0; t < 16; ++t) {
                f32x4 v = xp[t];
                xr[4 * t] = v[0]; xr[4 * t + 1] = v[1]; xr[4 * t + 2] = v[2]; xr[4 * t + 3] = v[3];
            }
            float cr = np_norm64(xr);
            float bd = 3.402823466e38f; int bj = 0;
            for (int t = 0; t < 16; ++t) {
                int j = lane * 16 + t;
                float d = exact_d(cr, se[j], exact_dot64(xr, w + j * 64));
                if (d < bd) { bd = d; bj = j; }
            }
            for (int mask = 1; mask < 64; mask <<= 1) {
                float od = __shfl_xor(bd, mask, 64);
                int   oj = __shfl_xor(bj, mask, 64);
                if (od < bd || (od == bd && oj < bj)) { bd = od; bj = oj; }
            }
            {
                #pragma clang fp contract(off)
                float xv = x[row * 64 + lane];
                float wv = w[bj * 64 + lane];
                float diff = wv - xv;
                part += diff * diff;
                out[QOFF + row * 64 + lane] = xv + diff;
            }
            if (lane == 0) out[IDXOFF + row] = (float)bj;
        }
    }

    for (int off = 32; off > 0; off >>= 1) part += __shfl_down(part, off, 64);
    if (lane == 0) sPart[wave] = part;
    __syncthreads();
    if (tid == 0) partial[NSCR + blockIdx.x] = (sPart[0] + sPart[1]) + (sPart[2] + sPart[3]);
}

// ---------- loss: single block sums the 2304 per-block partials, one writer ----------
__global__ __launch_bounds__(256) void vq_loss(const float* __restrict__ partial,
                                               float* __restrict__ out) {
    __shared__ float red[4];
    const int tid = threadIdx.x, lane = tid & 63, wave = tid >> 6;
    float s = 0.f;
    #pragma unroll
    for (int t = 0; t < 9; ++t) s += partial[t * 256 + tid];   // 9*256 = 2304 = NSCR+NFIN
    for (int off = 32; off > 0; off >>= 1) s += __shfl_down(s, off, 64);
    if (lane == 0) red[wave] = s;
    __syncthreads();
    if (tid == 0) out[0] = ((red[0] + red[1]) + (red[2] + red[3])) * (1.25f / 8388608.0f);
}

extern "C" void kernel_launch(void* const* d_in, const int* in_sizes, int n_in,
                              void* d_out, int out_size, void* d_ws, size_t ws_size,
                              hipStream_t stream) {
    const float* x = (const float*)d_in[0];
    const float* w = (const float*)d_in[1];
    float* out = (float*)d_out;

    unsigned short* Gf = (unsigned short*)d_ws;                  // 128 KB fragment-order fp16
    float* se   = (float*)((char*)d_ws + 131072);                // 4 KB
    float* se20 = (float*)((char*)d_ws + 135168);                // 4 KB
    int* flags  = (int*)((char*)d_ws + 139264);                  // 512 KB (every row written)
    float* partial = (float*)((char*)d_ws + 663552);             // 9 KB (2304 floats)

    vq_prep<<<32, 256, 0, stream>>>(w, Gf, se, se20);
    vq_screen<<<NSCR, 256, 0, stream>>>(x, w, Gf, se20, out, partial, flags);
    vq_finish<<<NFIN, 256, 0, stream>>>(x, w, se, out, partial, flags);
    vq_loss<<<1, 256, 0, stream>>>(partial, out);
}

// Round 6
// 262.093 us; speedup vs baseline: 1.6694x; 1.1385x over previous
//
#include <hip/hip_runtime.h>

#define NROWS   131072
#define DIM     64
#define K       1024
#define QOFF    1
#define IDXOFF  8388609        // 1 + NROWS*DIM
// Routing margin in 2^-20 distance units (~4.0e-4). Hard error bound of the
// fp16 screen is 2^-19 * sum|x_i| per distance; sound for sum|x_i| <= 104.8
// (11-sigma for chi-64 rows, P ~ 1e-23 across all rows), + 2 for trunc quant.
#define MQ      422
#define NSCR    2048           // screen grid (64 rows/block, 8 blocks/CU)
#define NFIN    512            // finish grid

typedef float    f32x4 __attribute__((ext_vector_type(4)));
typedef _Float16 f16x8 __attribute__((ext_vector_type(8)));

// ---------- np-exact arithmetic (validated: absmax 0.0) ----------
__device__ __forceinline__ float np_norm64(const float* v) {
    #pragma clang fp contract(off)
    float r[8];
    #pragma unroll
    for (int k = 0; k < 8; ++k) r[k] = v[k] * v[k];
    #pragma unroll
    for (int i = 8; i < 64; i += 8)
        #pragma unroll
        for (int k = 0; k < 8; ++k) r[k] += v[i + k] * v[i + k];
    return ((r[0] + r[1]) + (r[2] + r[3])) + ((r[4] + r[5]) + (r[6] + r[7]));
}
__device__ __forceinline__ float exact_dot64(const float* xr, const float* __restrict__ e) {
    float a0 = 0.f, a1 = 0.f, a2 = 0.f, a3 = 0.f;
    #pragma unroll
    for (int i = 0; i < 64; i += 4) {
        a0 = fmaf(xr[i + 0], e[i + 0], a0);
        a1 = fmaf(xr[i + 1], e[i + 1], a1);
        a2 = fmaf(xr[i + 2], e[i + 2], a2);
        a3 = fmaf(xr[i + 3], e[i + 3], a3);
    }
    return (a0 + a1) + (a2 + a3);
}
__device__ __forceinline__ float exact_d(float cr, float sej, float dot) {
    #pragma clang fp contract(off)
    float t = cr + sej;
    return t - 2.0f * dot;
}

// ---------- prep: W -> fp16(1024*e) in MFMA B-FRAGMENT ORDER + np-exact se ----------
// Gf layout: [ntile(64)][chunk(2)][lane(64)][8 halves].  Lane (quad,m16) of B-chunk c
// holds codes n = ntile*16+m16, k = c*32 + quad*8 + j  — exactly the 16x16x32 B fragment.
__global__ void vq_prep(const float* __restrict__ w, unsigned short* __restrict__ Gf,
                        float* __restrict__ se, float* __restrict__ se20) {
    int gid = blockIdx.x * 256 + threadIdx.x;       // 0..8191 = ntile*128 + c*64 + lane
    int lane = gid & 63, c = (gid >> 6) & 1, ntile = gid >> 7;
    int code = ntile * 16 + (lane & 15);
    int k0 = c * 32 + (lane >> 4) * 8;
    const float* rowp = w + code * 64 + k0;
    f16x8 h8;
    #pragma unroll
    for (int j = 0; j < 8; ++j) h8[j] = (_Float16)(rowp[j] * 1024.0f);  // *1024 exact; RNE
    *(f16x8*)(Gf + gid * 8) = h8;                    // fully coalesced 16B store
    if (gid < K) {
        #pragma clang fp contract(off)
        const float* e = w + gid * 64;
        float r[8];
        #pragma unroll
        for (int k2 = 0; k2 < 8; ++k2) r[k2] = e[k2] * e[k2];
        #pragma unroll
        for (int i = 8; i < 64; i += 8)
            #pragma unroll
            for (int k2 = 0; k2 < 8; ++k2) r[k2] += e[i + k2] * e[i + k2];
        float v = ((r[0] + r[1]) + (r[2] + r[3])) + ((r[4] + r[5]) + (r[6] + r[7]));
        se[gid] = v;
        se20[gid] = v * 1048576.0f;                 // exact (power of 2)
    }
}

// ---------- screen: barrierless fp16 MFMA scan + packed-int top-3 + dense-list output ----
// block = 256 (4 waves); ONE 16-row m-tile per wave; grid = 2048 (8 blocks/CU).
// Undecided rows are compacted via per-block LDS lists + ONE global atomicAdd per category
// per block (off the critical path), then coalesced copy-out to dense global lists.
__global__ __launch_bounds__(256, 8) void vq_screen(
    const float* __restrict__ x, const float* __restrict__ w,
    const unsigned short* __restrict__ Gf, const float* __restrict__ se20,
    float* __restrict__ out, float* __restrict__ partial, int* __restrict__ gcnt,
    int* __restrict__ pairRows, int* __restrict__ pairJJ, int* __restrict__ fullRows) {
    __shared__ float sSe[1024];         // 4 KB: se*2^20
    __shared__ float sPart[4];
    __shared__ int sCnt[2], sBase[2];
    __shared__ int sPairRow[64], sPairJJ[64], sFullRow[64];
    const int tid  = threadIdx.x;
    const int wave = tid >> 6, lane = tid & 63;
    const int quad = lane >> 4, m16 = lane & 15;
    const int wrow0 = blockIdx.x * 64 + wave * 16;

    if (tid < 2) sCnt[tid] = 0;
    #pragma unroll
    for (int t = 0; t < 4; ++t) sSe[t * 256 + tid] = se20[t * 256 + tid];

    // A fragment: fp16(x), A[m = m16][k = quad*8 + j], chunk c: k = 32c..32c+31
    f16x8 Ah[2];
    #pragma unroll
    for (int c = 0; c < 2; ++c) {
        const float* p = x + (wrow0 + m16) * 64 + c * 32 + quad * 8;
        f32x4 u0 = *(const f32x4*)p;
        f32x4 u1 = *(const f32x4*)(p + 4);
        #pragma unroll
        for (int j = 0; j < 8; ++j)
            Ah[c][j] = (_Float16)((j < 4) ? u0[j] : u1[j - 4]);
    }

    int m1[4], m2[4], m3[4];
    #pragma unroll
    for (int r = 0; r < 4; ++r) { m1[r] = 0x7fffffff; m2[r] = 0x7fffffff; m3[r] = 0x7fffffff; }

    __syncthreads();                    // sSe + sCnt ready

    #pragma unroll 4
    for (int t = 0; t < 64; ++t) {      // 64 code-tiles of 16
        f16x8 B0 = *(const f16x8*)(Gf + t * 1024 + lane * 8);        // chunk 0, coalesced
        f16x8 B1 = *(const f16x8*)(Gf + t * 1024 + 512 + lane * 8);  // chunk 1
        float sen = sSe[t * 16 + m16];
        int jn = t * 16 + m16;
        f32x4 acc = {0.f, 0.f, 0.f, 0.f};
        acc = __builtin_amdgcn_mfma_f32_16x16x32_f16(Ah[0], B0, acc, 0, 0, 0);
        acc = __builtin_amdgcn_mfma_f32_16x16x32_f16(Ah[1], B1, acc, 0, 0, 0);
        #pragma unroll
        for (int r = 0; r < 4; ++r) {
            // f*2^20 = se*2^20 - 2*2^-10*2^20*dot' ; dot' = 1024*x.e
            float kf = fmaf(acc[r], -2048.0f, sen);
            int q = (int)kf;                              // trunc: monotone
            int key = (int)((unsigned)q << 10) | jn;
            int a  = max(m2[r], key);                     // old m2
            int t2 = max(m1[r], key);                     // old m1
            m3[r] = min(m3[r], a);
            m2[r] = min(m2[r], t2);
            m1[r] = min(m1[r], key);
        }
    }

    // butterfly all-reduce top-3 over the 16 cols (C layout: col=m16, row=quad*4+r);
    // after the full butterfly EVERY lane holds the merged result for rows quad*4+r.
    #pragma unroll
    for (int mask = 1; mask <= 8; mask <<= 1) {
        #pragma unroll
        for (int r = 0; r < 4; ++r) {
            int b1 = __shfl_xor(m1[r], mask, 64);
            int b2 = __shfl_xor(m2[r], mask, 64);
            int b3 = __shfl_xor(m3[r], mask, 64);
            int lo1 = min(m1[r], b1), hi1 = max(m1[r], b1);
            int lo2 = min(m2[r], b2);
            m1[r] = lo1;
            m2[r] = min(hi1, lo2);
            m3[r] = min(max(hi1, lo2), min(m3[r], b3));
        }
    }

    int jd[4];                          // decided winner (or -1) for row quad*4+r, quad-uniform
    #pragma unroll
    for (int r = 0; r < 4; ++r) {
        int k1 = m1[r], k2 = m2[r], k3 = m3[r];
        int g21 = (k2 >> 10) - (k1 >> 10);
        int g31 = (k3 >> 10) - (k1 >> 10);
        int j1 = k1 & 1023;
        jd[r] = (g21 > MQ) ? j1 : -1;
        if (m16 == 0) {
            int rowG = wrow0 + quad * 4 + r;
            if (g21 > MQ) {
                out[IDXOFF + rowG] = (float)j1;
            } else if (g31 > MQ) {                         // winner in {j1, j2}
                int p = atomicAdd(&sCnt[0], 1);
                sPairRow[p] = rowG; sPairJJ[p] = j1 | ((k2 & 1023) << 10);
            } else {                                       // rare: full rescan
                int p = atomicAdd(&sCnt[1], 1);
                sFullRow[p] = rowG;
            }
        }
    }

    // q_st + loss for decided rows, coalesced: lane = dim; winner broadcast via static shfl
    float part = 0.f;
    #pragma unroll
    for (int i = 0; i < 16; ++i) {                         // row i = quad(i>>2)*4 + r(i&3)
        int jr = __shfl(jd[i & 3], (i >> 2) * 16, 64);
        if (jr >= 0) {
            #pragma clang fp contract(off)
            int rowG = wrow0 + i;
            float xv = x[rowG * 64 + lane];
            float wv = w[jr * 64 + lane];
            float diff = wv - xv;
            part += diff * diff;
            out[QOFF + rowG * 64 + lane] = xv + diff;
        }
    }
    for (int off = 32; off > 0; off >>= 1) part += __shfl_down(part, off, 64);
    if (lane == 0) sPart[wave] = part;
    __syncthreads();                    // sPart + LDS lists + sCnt final
    if (tid == 0) {
        partial[blockIdx.x] = (sPart[0] + sPart[1]) + (sPart[2] + sPart[3]);
        int np_ = sCnt[0], nf = sCnt[1];
        sBase[0] = np_ ? atomicAdd(&gcnt[0], np_) : 0;     // one atomic per block/category
        sBase[1] = nf  ? atomicAdd(&gcnt[1], nf)  : 0;
    }
    __syncthreads();                    // sBase ready
    if (tid < sCnt[0]) {
        int d = sBase[0] + tid;
        pairRows[d] = sPairRow[tid]; pairJJ[d] = sPairJJ[tid];
    }
    if (tid < sCnt[1]) fullRows[sBase[1] + tid] = sFullRow[tid];
}

// ---------- finish: dense lists; exact pair-compares (thread) + full rescans (wave) -----
__global__ __launch_bounds__(256) void vq_finish(
    const float* __restrict__ x, const float* __restrict__ w, const float* __restrict__ se,
    float* __restrict__ out, float* __restrict__ partial, const int* __restrict__ gcnt,
    const int* __restrict__ pairRows, const int* __restrict__ pairJJ,
    const int* __restrict__ fullRows) {
    __shared__ float sPart[4];
    const int tid = threadIdx.x;
    const int lane = tid & 63, wave = tid >> 6;
    const int nPair = gcnt[0], nFull = gcnt[1];
    const int gthread = blockIdx.x * 256 + tid, nThreads = gridDim.x * 256;
    const int gwave = blockIdx.x * 4 + wave,   nWaves = gridDim.x * 4;
    float part = 0.f;

    // Phase A: winner in {ja, jb}; exact compare with np first-index tie rule
    for (int i = gthread; i < nPair; i += nThreads) {
        int row = pairRows[i], jj = pairJJ[i];
        int ja = jj & 1023, jb = (jj >> 10) & 1023;
        if (ja > jb) { int t = ja; ja = jb; jb = t; }
        float xr[64];
        const f32x4* xp = (const f32x4*)(x + row * 64);
        #pragma unroll
        for (int t = 0; t < 16; ++t) {
            f32x4 v = xp[t];
            xr[4 * t] = v[0]; xr[4 * t + 1] = v[1]; xr[4 * t + 2] = v[2]; xr[4 * t + 3] = v[3];
        }
        float cr = np_norm64(xr);
        float da = exact_d(cr, se[ja], exact_dot64(xr, w + ja * 64));
        float db = exact_d(cr, se[jb], exact_dot64(xr, w + jb * 64));
        int win = (db < da) ? jb : ja;
        out[IDXOFF + row] = (float)win;
        const float* e = w + win * 64;
        {
            #pragma clang fp contract(off)
            #pragma unroll
            for (int i2 = 0; i2 < 64; ++i2) {
                float diff = e[i2] - xr[i2];
                part += diff * diff;
                out[QOFF + row * 64 + i2] = xr[i2] + diff;
            }
        }
    }

    // Phase B: full exact rescan, one row per wave (16 codes per lane)
    for (int i = gwave; i < nFull; i += nWaves) {
        int row = fullRows[i];
        float xr[64];
        const f32x4* xp = (const f32x4*)(x + row * 64);
        #pragma unroll
        for (int t = 0; t < 16; ++t) {
            f32x4 v = xp[t];
            xr[4 * t] = v[0]; xr[4 * t + 1] = v[1]; xr[4 * t + 2] = v[2]; xr[4 * t + 3] = v[3];
        }
        float cr = np_norm64(xr);
        float bd = 3.402823466e38f; int bj = 0;
        for (int t = 0; t < 16; ++t) {
            int j = lane * 16 + t;
            float d = exact_d(cr, se[j], exact_dot64(xr, w + j * 64));
            if (d < bd) { bd = d; bj = j; }
        }
        for (int mask = 1; mask < 64; mask <<= 1) {
            float od = __shfl_xor(bd, mask, 64);
            int   oj = __shfl_xor(bj, mask, 64);
            if (od < bd || (od == bd && oj < bj)) { bd = od; bj = oj; }
        }
        {
            #pragma clang fp contract(off)
            float xv = x[row * 64 + lane];
            float wv = w[bj * 64 + lane];
            float diff = wv - xv;
            part += diff * diff;
            out[QOFF + row * 64 + lane] = xv + diff;
        }
        if (lane == 0) out[IDXOFF + row] = (float)bj;
    }

    for (int off = 32; off > 0; off >>= 1) part += __shfl_down(part, off, 64);
    if (lane == 0) sPart[wave] = part;
    __syncthreads();
    if (tid == 0) partial[NSCR + blockIdx.x] = (sPart[0] + sPart[1]) + (sPart[2] + sPart[3]);
}

// ---------- loss: single block sums the 2560 per-block partials, one writer ----------
__global__ __launch_bounds__(256) void vq_loss(const float* __restrict__ partial,
                                               float* __restrict__ out) {
    __shared__ float red[4];
    const int tid = threadIdx.x, lane = tid & 63, wave = tid >> 6;
    float s = 0.f;
    #pragma unroll
    for (int t = 0; t < 10; ++t) s += partial[t * 256 + tid];  // 10*256 = 2560 = NSCR+NFIN
    for (int off = 32; off > 0; off >>= 1) s += __shfl_down(s, off, 64);
    if (lane == 0) red[wave] = s;
    __syncthreads();
    if (tid == 0) out[0] = ((red[0] + red[1]) + (red[2] + red[3])) * (1.25f / 8388608.0f);
}

extern "C" void kernel_launch(void* const* d_in, const int* in_sizes, int n_in,
                              void* d_out, int out_size, void* d_ws, size_t ws_size,
                              hipStream_t stream) {
    const float* x = (const float*)d_in[0];
    const float* w = (const float*)d_in[1];
    float* out = (float*)d_out;

    unsigned short* Gf = (unsigned short*)d_ws;                  // 128 KB fragment-order fp16
    float* se   = (float*)((char*)d_ws + 131072);                // 4 KB
    float* se20 = (float*)((char*)d_ws + 135168);                // 4 KB
    int* gcnt   = (int*)((char*)d_ws + 139264);                  // 8 B (pad to 512)
    int* pairRows = (int*)((char*)d_ws + 139776);                // 512 KB worst case
    int* pairJJ   = pairRows + NROWS;                            // 512 KB
    int* fullRows = pairJJ + NROWS;                              // 512 KB
    float* partial = (float*)(fullRows + NROWS);                 // 10 KB (2560 floats)

    (void)hipMemsetAsync(gcnt, 0, 2 * sizeof(int), stream);
    vq_prep<<<32, 256, 0, stream>>>(w, Gf, se, se20);
    vq_screen<<<NSCR, 256, 0, stream>>>(x, w, Gf, se20, out, partial, gcnt,
                                        pairRows, pairJJ, fullRows);
    vq_finish<<<NFIN, 256, 0, stream>>>(x, w, se, out, partial, gcnt,
                                        pairRows, pairJJ, fullRows);
    vq_loss<<<1, 256, 0, stream>>>(partial, out);
}

// Round 7
// 185.882 us; speedup vs baseline: 2.3538x; 1.4100x over previous
//
#include <hip/hip_runtime.h>

#define NROWS   131072
#define DIM     64
#define K       1024
#define QOFF    1
#define IDXOFF  8388609        // 1 + NROWS*DIM
// Per-row routing margin in 2^-20 distance units: hard error of the fp16 screen
// is 2^-19 * sum|x_i| per distance => 2*S units.  mq = 2.002*S + 5 covers
// fp32 S-summation slack, MFMA fp32 accumulation (<=1), trunc quant (2), ceil (1).
#define NSCR    2048           // screen grid (64 rows/block, 8 blocks/CU)
#define NFIN    512            // finish grid

typedef float    f32x4 __attribute__((ext_vector_type(4)));
typedef _Float16 f16x8 __attribute__((ext_vector_type(8)));

// ---------- np-exact arithmetic (validated: absmax 0.0) ----------
__device__ __forceinline__ float np_norm64(const float* v) {
    #pragma clang fp contract(off)
    float r[8];
    #pragma unroll
    for (int k = 0; k < 8; ++k) r[k] = v[k] * v[k];
    #pragma unroll
    for (int i = 8; i < 64; i += 8)
        #pragma unroll
        for (int k = 0; k < 8; ++k) r[k] += v[i + k] * v[i + k];
    return ((r[0] + r[1]) + (r[2] + r[3])) + ((r[4] + r[5]) + (r[6] + r[7]));
}
__device__ __forceinline__ float exact_dot64(const float* xr, const float* __restrict__ e) {
    float a0 = 0.f, a1 = 0.f, a2 = 0.f, a3 = 0.f;
    #pragma unroll
    for (int i = 0; i < 64; i += 4) {
        a0 = fmaf(xr[i + 0], e[i + 0], a0);
        a1 = fmaf(xr[i + 1], e[i + 1], a1);
        a2 = fmaf(xr[i + 2], e[i + 2], a2);
        a3 = fmaf(xr[i + 3], e[i + 3], a3);
    }
    return (a0 + a1) + (a2 + a3);
}
__device__ __forceinline__ float exact_d(float cr, float sej, float dot) {
    #pragma clang fp contract(off)
    float t = cr + sej;
    return t - 2.0f * dot;
}

// ---------- prep: Gf (fp16 fragment-order), wT (column-major fp32), se/se20 ----------
__global__ void vq_prep(const float* __restrict__ w, unsigned short* __restrict__ Gf,
                        float* __restrict__ wT, float* __restrict__ se,
                        float* __restrict__ se20) {
    int gid = blockIdx.x * 256 + threadIdx.x;       // 0..8191 = ntile*128 + c*64 + lane
    int lane = gid & 63, c = (gid >> 6) & 1, ntile = gid >> 7;
    int code = ntile * 16 + (lane & 15);
    int k0 = c * 32 + (lane >> 4) * 8;
    const float* rowp = w + code * 64 + k0;
    f16x8 h8;
    #pragma unroll
    for (int j = 0; j < 8; ++j) h8[j] = (_Float16)(rowp[j] * 1024.0f);  // *1024 exact; RNE
    *(f16x8*)(Gf + gid * 8) = h8;                    // fully coalesced 16B store
    // transpose: wT[i*1024 + j] = w[j*64 + i]  (coalesced writes)
    #pragma unroll
    for (int t = 0; t < 8; ++t) {
        int flat = t * 8192 + gid;                   // 0..65535
        int i = flat >> 10, j = flat & 1023;
        wT[flat] = w[j * 64 + i];
    }
    if (gid < K) {
        #pragma clang fp contract(off)
        const float* e = w + gid * 64;
        float r[8];
        #pragma unroll
        for (int k2 = 0; k2 < 8; ++k2) r[k2] = e[k2] * e[k2];
        #pragma unroll
        for (int i = 8; i < 64; i += 8)
            #pragma unroll
            for (int k2 = 0; k2 < 8; ++k2) r[k2] += e[i + k2] * e[i + k2];
        float v = ((r[0] + r[1]) + (r[2] + r[3])) + ((r[4] + r[5]) + (r[6] + r[7]));
        se[gid] = v;
        se20[gid] = v * 1048576.0f;                 // exact (power of 2)
    }
}

// ---------- screen: barrierless fp16 MFMA scan + packed-int top-3 + dense-list output ----
// block = 256 (4 waves); ONE 16-row m-tile per wave; grid = 2048 (8 blocks/CU).
// Per-row margin mq = 2.002*sum|x_i| + 5 (hard bound).  Undecided rows compacted via LDS
// lists + one global atomicAdd per category per block.
__global__ __launch_bounds__(256, 8) void vq_screen(
    const float* __restrict__ x, const float* __restrict__ w,
    const unsigned short* __restrict__ Gf, const float* __restrict__ se20,
    float* __restrict__ out, float* __restrict__ partial, int* __restrict__ gcnt,
    int* __restrict__ pairRows, int* __restrict__ pairJJ, int* __restrict__ fullRows) {
    __shared__ float sSe[1024];         // 4 KB: se*2^20
    __shared__ float sPart[4];
    __shared__ int sCnt[2], sBase[2];
    __shared__ int sPairRow[64], sPairJJ[64], sFullRow[64];
    const int tid  = threadIdx.x;
    const int wave = tid >> 6, lane = tid & 63;
    const int quad = lane >> 4, m16 = lane & 15;
    const int wrow0 = blockIdx.x * 64 + wave * 16;

    if (tid < 2) sCnt[tid] = 0;
    #pragma unroll
    for (int t = 0; t < 4; ++t) sSe[t * 256 + tid] = se20[t * 256 + tid];

    // A fragment: fp16(x), A[m = m16][k = quad*8 + j], chunk c: k = 32c..32c+31
    // Sloc accumulates this lane's 16 |x| terms; quad-reduce => S(row m16) on every lane.
    f16x8 Ah[2];
    float Sloc = 0.f;
    #pragma unroll
    for (int c = 0; c < 2; ++c) {
        const float* p = x + (wrow0 + m16) * 64 + c * 32 + quad * 8;
        f32x4 u0 = *(const f32x4*)p;
        f32x4 u1 = *(const f32x4*)(p + 4);
        #pragma unroll
        for (int j = 0; j < 8; ++j) {
            float xv = (j < 4) ? u0[j] : u1[j - 4];
            Ah[c][j] = (_Float16)xv;
            Sloc += fabsf(xv);
        }
    }
    Sloc += __shfl_xor(Sloc, 16, 64);
    Sloc += __shfl_xor(Sloc, 32, 64);   // every lane: S(row = its m16)

    int m1[4], m2[4], m3[4];
    #pragma unroll
    for (int r = 0; r < 4; ++r) { m1[r] = 0x7fffffff; m2[r] = 0x7fffffff; m3[r] = 0x7fffffff; }

    __syncthreads();                    // sSe + sCnt ready

    #pragma unroll 4
    for (int t = 0; t < 64; ++t) {      // 64 code-tiles of 16
        f16x8 B0 = *(const f16x8*)(Gf + t * 1024 + lane * 8);        // chunk 0, coalesced
        f16x8 B1 = *(const f16x8*)(Gf + t * 1024 + 512 + lane * 8);  // chunk 1
        float sen = sSe[t * 16 + m16];
        int jn = t * 16 + m16;
        f32x4 acc = {0.f, 0.f, 0.f, 0.f};
        acc = __builtin_amdgcn_mfma_f32_16x16x32_f16(Ah[0], B0, acc, 0, 0, 0);
        acc = __builtin_amdgcn_mfma_f32_16x16x32_f16(Ah[1], B1, acc, 0, 0, 0);
        #pragma unroll
        for (int r = 0; r < 4; ++r) {
            // f*2^20 = se*2^20 - 2*2^-10*2^20*dot' ; dot' = 1024*x.e
            float kf = fmaf(acc[r], -2048.0f, sen);
            int q = (int)kf;                              // trunc: monotone
            int key = (int)((unsigned)q << 10) | jn;
            int a  = max(m2[r], key);                     // old m2
            int t2 = max(m1[r], key);                     // old m1
            m3[r] = min(m3[r], a);
            m2[r] = min(m2[r], t2);
            m1[r] = min(m1[r], key);
        }
    }

    // butterfly all-reduce top-3 over the 16 cols (C layout: col=m16, row=quad*4+r);
    // after the full butterfly EVERY lane holds the merged result for rows quad*4+r.
    #pragma unroll
    for (int mask = 1; mask <= 8; mask <<= 1) {
        #pragma unroll
        for (int r = 0; r < 4; ++r) {
            int b1 = __shfl_xor(m1[r], mask, 64);
            int b2 = __shfl_xor(m2[r], mask, 64);
            int b3 = __shfl_xor(m3[r], mask, 64);
            int lo1 = min(m1[r], b1), hi1 = max(m1[r], b1);
            int lo2 = min(m2[r], b2);
            m1[r] = lo1;
            m2[r] = min(hi1, lo2);
            m3[r] = min(max(hi1, lo2), min(m3[r], b3));
        }
    }

    int jd[4];                          // decided winner (or -1) for row quad*4+r, quad-uniform
    #pragma unroll
    for (int r = 0; r < 4; ++r) {
        int k1 = m1[r], k2 = m2[r], k3 = m3[r];
        int g21 = (k2 >> 10) - (k1 >> 10);
        int g31 = (k3 >> 10) - (k1 >> 10);
        int j1 = k1 & 1023;
        float Srow = __shfl(Sloc, quad * 4 + r, 64);       // S of row quad*4+r
        int mq = (int)(Srow * 2.002f) + 5;                 // per-row hard margin
        jd[r] = (g21 > mq) ? j1 : -1;
        if (m16 == 0) {
            int rowG = wrow0 + quad * 4 + r;
            if (g21 > mq) {
                out[IDXOFF + rowG] = (float)j1;
            } else if (g31 > mq) {                         // winner in {j1, j2}
                int p = atomicAdd(&sCnt[0], 1);
                sPairRow[p] = rowG; sPairJJ[p] = j1 | ((k2 & 1023) << 10);
            } else {                                       // rare: full rescan
                int p = atomicAdd(&sCnt[1], 1);
                sFullRow[p] = rowG;
            }
        }
    }

    // q_st + loss for decided rows, coalesced: lane = dim; winner broadcast via static shfl
    float part = 0.f;
    #pragma unroll
    for (int i = 0; i < 16; ++i) {                         // row i = quad(i>>2)*4 + r(i&3)
        int jr = __shfl(jd[i & 3], (i >> 2) * 16, 64);
        if (jr >= 0) {
            #pragma clang fp contract(off)
            int rowG = wrow0 + i;
            float xv = x[rowG * 64 + lane];
            float wv = w[jr * 64 + lane];
            float diff = wv - xv;
            part += diff * diff;
            out[QOFF + rowG * 64 + lane] = xv + diff;
        }
    }
    for (int off = 32; off > 0; off >>= 1) part += __shfl_down(part, off, 64);
    if (lane == 0) sPart[wave] = part;
    __syncthreads();                    // sPart + LDS lists + sCnt final
    if (tid == 0) {
        partial[blockIdx.x] = (sPart[0] + sPart[1]) + (sPart[2] + sPart[3]);
        int np_ = sCnt[0], nf = sCnt[1];
        sBase[0] = np_ ? atomicAdd(&gcnt[0], np_) : 0;     // one atomic per block/category
        sBase[1] = nf  ? atomicAdd(&gcnt[1], nf)  : 0;
    }
    __syncthreads();                    // sBase ready
    if (tid < sCnt[0]) {
        int d = sBase[0] + tid;
        pairRows[d] = sPairRow[tid]; pairJJ[d] = sPairJJ[tid];
    }
    if (tid < sCnt[1]) fullRows[sBase[1] + tid] = sFullRow[tid];
}

// ---------- finish: dense lists; exact pair-compares (thread) + coalesced full rescans ----
__global__ __launch_bounds__(256) void vq_finish(
    const float* __restrict__ x, const float* __restrict__ w, const float* __restrict__ wT,
    const float* __restrict__ se, float* __restrict__ out, float* __restrict__ partial,
    const int* __restrict__ gcnt, const int* __restrict__ pairRows,
    const int* __restrict__ pairJJ, const int* __restrict__ fullRows) {
    __shared__ float sPart[4];
    const int tid = threadIdx.x;
    const int lane = tid & 63, wave = tid >> 6;
    const int nPair = gcnt[0], nFull = gcnt[1];
    const int gthread = blockIdx.x * 256 + tid, nThreads = gridDim.x * 256;
    const int gwave = blockIdx.x * 4 + wave,   nWaves = gridDim.x * 4;
    float part = 0.f;

    // Phase A: winner in {ja, jb}; exact compare with np first-index tie rule
    for (int i = gthread; i < nPair; i += nThreads) {
        int row = pairRows[i], jj = pairJJ[i];
        int ja = jj & 1023, jb = (jj >> 10) & 1023;
        if (ja > jb) { int t = ja; ja = jb; jb = t; }
        float xr[64];
        const f32x4* xp = (const f32x4*)(x + row * 64);
        #pragma unroll
        for (int t = 0; t < 16; ++t) {
            f32x4 v = xp[t];
            xr[4 * t] = v[0]; xr[4 * t + 1] = v[1]; xr[4 * t + 2] = v[2]; xr[4 * t + 3] = v[3];
        }
        float cr = np_norm64(xr);
        float da = exact_d(cr, se[ja], exact_dot64(xr, w + ja * 64));
        float db = exact_d(cr, se[jb], exact_dot64(xr, w + jb * 64));
        int win = (db < da) ? jb : ja;
        out[IDXOFF + row] = (float)win;
        const float* e = w + win * 64;
        {
            #pragma clang fp contract(off)
            #pragma unroll
            for (int i2 = 0; i2 < 64; ++i2) {
                float diff = e[i2] - xr[i2];
                part += diff * diff;
                out[QOFF + row * 64 + i2] = xr[i2] + diff;
            }
        }
    }

    // Phase B: full exact rescan, one row per wave.  Coalesced: lane owns 4 consecutive
    // codes per pass (f32x4 over codes from wT), dims iterate outer; the 4-stripe
    // accumulator order (q = i&3, dims ascending) is bit-identical to exact_dot64.
    const f32x4* wT4 = (const f32x4*)wT;
    for (int i = gwave; i < nFull; i += nWaves) {
        int row = fullRows[i];
        float xr[64];                                    // same row for all lanes (broadcast)
        const f32x4* xp = (const f32x4*)(x + row * 64);
        #pragma unroll
        for (int t = 0; t < 16; ++t) {
            f32x4 v = xp[t];
            xr[4 * t] = v[0]; xr[4 * t + 1] = v[1]; xr[4 * t + 2] = v[2]; xr[4 * t + 3] = v[3];
        }
        float cr = np_norm64(xr);
        float bd = 3.402823466e38f; int bj = 0;
        #pragma unroll
        for (int g = 0; g < 4; ++g) {                    // pass g: codes g*256 + 4*lane + c
            f32x4 a0 = {0.f,0.f,0.f,0.f}, a1 = a0, a2 = a0, a3 = a0;
            #pragma unroll 4
            for (int i2 = 0; i2 < 64; i2 += 4) {
                f32x4 w0 = wT4[(i2 + 0) * 256 + g * 64 + lane];
                f32x4 w1 = wT4[(i2 + 1) * 256 + g * 64 + lane];
                f32x4 w2 = wT4[(i2 + 2) * 256 + g * 64 + lane];
                f32x4 w3 = wT4[(i2 + 3) * 256 + g * 64 + lane];
                #pragma unroll
                for (int c = 0; c < 4; ++c) {
                    a0[c] = fmaf(xr[i2 + 0], w0[c], a0[c]);
                    a1[c] = fmaf(xr[i2 + 1], w1[c], a1[c]);
                    a2[c] = fmaf(xr[i2 + 2], w2[c], a2[c]);
                    a3[c] = fmaf(xr[i2 + 3], w3[c], a3[c]);
                }
            }
            #pragma unroll
            for (int c = 0; c < 4; ++c) {
                float dot = (a0[c] + a1[c]) + (a2[c] + a3[c]);
                int j = g * 256 + lane * 4 + c;
                float d = exact_d(cr, se[j], dot);
                if (d < bd) { bd = d; bj = j; }          // per-lane j ascending => np tie rule
            }
        }
        for (int mask = 1; mask < 64; mask <<= 1) {
            float od = __shfl_xor(bd, mask, 64);
            int   oj = __shfl_xor(bj, mask, 64);
            if (od < bd || (od == bd && oj < bj)) { bd = od; bj = oj; }
        }
        {
            #pragma clang fp contract(off)
            float xv = x[row * 64 + lane];
            float wv = w[bj * 64 + lane];
            float diff = wv - xv;
            part += diff * diff;
            out[QOFF + row * 64 + lane] = xv + diff;
        }
        if (lane == 0) out[IDXOFF + row] = (float)bj;
    }

    for (int off = 32; off > 0; off >>= 1) part += __shfl_down(part, off, 64);
    if (lane == 0) sPart[wave] = part;
    __syncthreads();
    if (tid == 0) partial[NSCR + blockIdx.x] = (sPart[0] + sPart[1]) + (sPart[2] + sPart[3]);
}

// ---------- loss: single block sums the 2560 per-block partials, one writer ----------
__global__ __launch_bounds__(256) void vq_loss(const float* __restrict__ partial,
                                               float* __restrict__ out) {
    __shared__ float red[4];
    const int tid = threadIdx.x, lane = tid & 63, wave = tid >> 6;
    float s = 0.f;
    #pragma unroll
    for (int t = 0; t < 10; ++t) s += partial[t * 256 + tid];  // 10*256 = 2560 = NSCR+NFIN
    for (int off = 32; off > 0; off >>= 1) s += __shfl_down(s, off, 64);
    if (lane == 0) red[wave] = s;
    __syncthreads();
    if (tid == 0) out[0] = ((red[0] + red[1]) + (red[2] + red[3])) * (1.25f / 8388608.0f);
}

extern "C" void kernel_launch(void* const* d_in, const int* in_sizes, int n_in,
                              void* d_out, int out_size, void* d_ws, size_t ws_size,
                              hipStream_t stream) {
    const float* x = (const float*)d_in[0];
    const float* w = (const float*)d_in[1];
    float* out = (float*)d_out;

    unsigned short* Gf = (unsigned short*)d_ws;                  // 128 KB fragment-order fp16
    float* se   = (float*)((char*)d_ws + 131072);                // 4 KB
    float* se20 = (float*)((char*)d_ws + 135168);                // 4 KB
    float* wT   = (float*)((char*)d_ws + 139264);                // 256 KB column-major fp32
    int* gcnt   = (int*)((char*)d_ws + 401408);                  // 8 B (pad to 512)
    int* pairRows = (int*)((char*)d_ws + 401920);                // 512 KB worst case
    int* pairJJ   = pairRows + NROWS;                            // 512 KB
    int* fullRows = pairJJ + NROWS;                              // 512 KB
    float* partial = (float*)(fullRows + NROWS);                 // 10 KB (2560 floats)

    (void)hipMemsetAsync(gcnt, 0, 2 * sizeof(int), stream);
    vq_prep<<<32, 256, 0, stream>>>(w, Gf, wT, se, se20);
    vq_screen<<<NSCR, 256, 0, stream>>>(x, w, Gf, se20, out, partial, gcnt,
                                        pairRows, pairJJ, fullRows);
    vq_finish<<<NFIN, 256, 0, stream>>>(x, w, wT, se, out, partial, gcnt,
                                        pairRows, pairJJ, fullRows);
    vq_loss<<<1, 256, 0, stream>>>(partial, out);
}

// Round 8
// 184.682 us; speedup vs baseline: 2.3691x; 1.0065x over previous
//
#include <hip/hip_runtime.h>

#define NROWS   131072
#define DIM     64
#define K       1024
#define QOFF    1
#define IDXOFF  8388609        // 1 + NROWS*DIM
// Per-row routing margin in 2^-20 distance units: hard error of the fp16 screen
// is 2^-19 * sum|x_i| per distance => 2*S units.  mq = 2.002*S + 5 covers
// fp32 S-summation slack, MFMA fp32 accumulation (<=1), trunc quant (2), ceil (1).
#define NSCR    1024           // screen grid (128 rows/block, 4 blocks/CU)
#define NFIN    512            // finish grid

typedef float    f32x4 __attribute__((ext_vector_type(4)));
typedef _Float16 f16x8 __attribute__((ext_vector_type(8)));

// ---------- np-exact arithmetic (validated: absmax 0.0) ----------
__device__ __forceinline__ float np_norm64(const float* v) {
    #pragma clang fp contract(off)
    float r[8];
    #pragma unroll
    for (int k = 0; k < 8; ++k) r[k] = v[k] * v[k];
    #pragma unroll
    for (int i = 8; i < 64; i += 8)
        #pragma unroll
        for (int k = 0; k < 8; ++k) r[k] += v[i + k] * v[i + k];
    return ((r[0] + r[1]) + (r[2] + r[3])) + ((r[4] + r[5]) + (r[6] + r[7]));
}
__device__ __forceinline__ float exact_dot64(const float* xr, const float* __restrict__ e) {
    float a0 = 0.f, a1 = 0.f, a2 = 0.f, a3 = 0.f;
    #pragma unroll
    for (int i = 0; i < 64; i += 4) {
        a0 = fmaf(xr[i + 0], e[i + 0], a0);
        a1 = fmaf(xr[i + 1], e[i + 1], a1);
        a2 = fmaf(xr[i + 2], e[i + 2], a2);
        a3 = fmaf(xr[i + 3], e[i + 3], a3);
    }
    return (a0 + a1) + (a2 + a3);
}
__device__ __forceinline__ float exact_d(float cr, float sej, float dot) {
    #pragma clang fp contract(off)
    float t = cr + sej;
    return t - 2.0f * dot;
}

// ---------- prep: Gf (fp16 fragment-order), wT (column-major fp32), se/se20, gcnt=0 ----
__global__ void vq_prep(const float* __restrict__ w, unsigned short* __restrict__ Gf,
                        float* __restrict__ wT, float* __restrict__ se,
                        float* __restrict__ se20, int* __restrict__ gcnt) {
    int gid = blockIdx.x * 256 + threadIdx.x;       // 0..8191 = ntile*128 + c*64 + lane
    if (gid < 2) gcnt[gid] = 0;
    int lane = gid & 63, c = (gid >> 6) & 1, ntile = gid >> 7;
    int code = ntile * 16 + (lane & 15);
    int k0 = c * 32 + (lane >> 4) * 8;
    const float* rowp = w + code * 64 + k0;
    f16x8 h8;
    #pragma unroll
    for (int j = 0; j < 8; ++j) h8[j] = (_Float16)(rowp[j] * 1024.0f);  // *1024 exact; RNE
    *(f16x8*)(Gf + gid * 8) = h8;                    // fully coalesced 16B store
    // transpose: wT[i*1024 + j] = w[j*64 + i]  (coalesced writes)
    #pragma unroll
    for (int t = 0; t < 8; ++t) {
        int flat = t * 8192 + gid;                   // 0..65535
        int i = flat >> 10, j = flat & 1023;
        wT[flat] = w[j * 64 + i];
    }
    if (gid < K) {
        #pragma clang fp contract(off)
        const float* e = w + gid * 64;
        float r[8];
        #pragma unroll
        for (int k2 = 0; k2 < 8; ++k2) r[k2] = e[k2] * e[k2];
        #pragma unroll
        for (int i = 8; i < 64; i += 8)
            #pragma unroll
            for (int k2 = 0; k2 < 8; ++k2) r[k2] += e[i + k2] * e[i + k2];
        float v = ((r[0] + r[1]) + (r[2] + r[3])) + ((r[4] + r[5]) + (r[6] + r[7]));
        se[gid] = v;
        se20[gid] = v * 1048576.0f;                 // exact (power of 2)
    }
}

// ---------- screen: barrierless fp16 MFMA scan, 2 m-tiles/wave, packed-int top-3 --------
// block = 256 (4 waves); TWO 16-row m-tiles per wave (32 rows); grid = 1024 (4 blocks/CU,
// 16 waves/CU).  Each B-tile load from L2 now feeds 2 MFMAs per operand => codebook L2
// traffic halves vs 1 m-tile.  Per-row margin mq = 2.002*sum|x_i| + 5 (hard bound).
__global__ __launch_bounds__(256, 4) void vq_screen(
    const float* __restrict__ x, const float* __restrict__ w,
    const unsigned short* __restrict__ Gf, const float* __restrict__ se20,
    float* __restrict__ out, float* __restrict__ partial, int* __restrict__ gcnt,
    int* __restrict__ pairRows, int* __restrict__ pairJJ, int* __restrict__ fullRows) {
    __shared__ float sSe[1024];         // 4 KB: se*2^20
    __shared__ float sPart[4];
    __shared__ int sCnt[2], sBase[2];
    __shared__ int sPairRow[128], sPairJJ[128], sFullRow[128];
    const int tid  = threadIdx.x;
    const int wave = tid >> 6, lane = tid & 63;
    const int quad = lane >> 4, m16 = lane & 15;
    const int wrow0 = blockIdx.x * 128 + wave * 32;

    if (tid < 2) sCnt[tid] = 0;
    #pragma unroll
    for (int t = 0; t < 4; ++t) sSe[t * 256 + tid] = se20[t * 256 + tid];

    // A fragments: fp16(x), A[m = m16][k = quad*8 + j], chunk c: k = 32c..32c+31
    // Sloc[mt] accumulates this lane's 16 |x| terms; quad-reduce => S(row m16) per mt.
    f16x8 Ah[2][2];
    float Sloc[2] = {0.f, 0.f};
    #pragma unroll
    for (int mt = 0; mt < 2; ++mt)
        #pragma unroll
        for (int c = 0; c < 2; ++c) {
            const float* p = x + (wrow0 + mt * 16 + m16) * 64 + c * 32 + quad * 8;
            f32x4 u0 = *(const f32x4*)p;
            f32x4 u1 = *(const f32x4*)(p + 4);
            #pragma unroll
            for (int j = 0; j < 8; ++j) {
                float xv = (j < 4) ? u0[j] : u1[j - 4];
                Ah[mt][c][j] = (_Float16)xv;
                Sloc[mt] += fabsf(xv);
            }
        }
    #pragma unroll
    for (int mt = 0; mt < 2; ++mt) {
        Sloc[mt] += __shfl_xor(Sloc[mt], 16, 64);
        Sloc[mt] += __shfl_xor(Sloc[mt], 32, 64);   // every lane: S(row = its m16)
    }

    int m1[2][4], m2[2][4], m3[2][4];
    #pragma unroll
    for (int mt = 0; mt < 2; ++mt)
        #pragma unroll
        for (int r = 0; r < 4; ++r) {
            m1[mt][r] = 0x7fffffff; m2[mt][r] = 0x7fffffff; m3[mt][r] = 0x7fffffff;
        }

    __syncthreads();                    // sSe + sCnt ready (only barrier before epilogue)

    #pragma unroll 8
    for (int t = 0; t < 64; ++t) {      // 64 code-tiles of 16
        f16x8 B0 = *(const f16x8*)(Gf + t * 1024 + lane * 8);        // chunk 0, coalesced
        f16x8 B1 = *(const f16x8*)(Gf + t * 1024 + 512 + lane * 8);  // chunk 1
        float sen = sSe[t * 16 + m16];
        int jn = t * 16 + m16;
        #pragma unroll
        for (int mt = 0; mt < 2; ++mt) {
            f32x4 acc = {0.f, 0.f, 0.f, 0.f};
            acc = __builtin_amdgcn_mfma_f32_16x16x32_f16(Ah[mt][0], B0, acc, 0, 0, 0);
            acc = __builtin_amdgcn_mfma_f32_16x16x32_f16(Ah[mt][1], B1, acc, 0, 0, 0);
            #pragma unroll
            for (int r = 0; r < 4; ++r) {
                // f*2^20 = se*2^20 - 2*2^-10*2^20*dot' ; dot' = 1024*x.e
                float kf = fmaf(acc[r], -2048.0f, sen);
                int q = (int)kf;                              // trunc: monotone
                int key = (int)((unsigned)q << 10) | jn;
                int a  = max(m2[mt][r], key);                 // old m2
                int t2 = max(m1[mt][r], key);                 // old m1
                m3[mt][r] = min(m3[mt][r], a);
                m2[mt][r] = min(m2[mt][r], t2);
                m1[mt][r] = min(m1[mt][r], key);
            }
        }
    }

    // butterfly all-reduce top-3 over the 16 cols (C layout: col=m16, row=quad*4+r);
    // after the full butterfly EVERY lane holds the merged result for rows quad*4+r.
    #pragma unroll
    for (int mask = 1; mask <= 8; mask <<= 1) {
        #pragma unroll
        for (int mt = 0; mt < 2; ++mt)
            #pragma unroll
            for (int r = 0; r < 4; ++r) {
                int b1 = __shfl_xor(m1[mt][r], mask, 64);
                int b2 = __shfl_xor(m2[mt][r], mask, 64);
                int b3 = __shfl_xor(m3[mt][r], mask, 64);
                int lo1 = min(m1[mt][r], b1), hi1 = max(m1[mt][r], b1);
                int lo2 = min(m2[mt][r], b2);
                m1[mt][r] = lo1;
                m2[mt][r] = min(hi1, lo2);
                m3[mt][r] = min(max(hi1, lo2), min(m3[mt][r], b3));
            }
    }

    int jd[2][4];                       // decided winner (or -1) per mt, row quad*4+r
    #pragma unroll
    for (int mt = 0; mt < 2; ++mt)
        #pragma unroll
        for (int r = 0; r < 4; ++r) {
            int k1 = m1[mt][r], k2 = m2[mt][r], k3 = m3[mt][r];
            int g21 = (k2 >> 10) - (k1 >> 10);
            int g31 = (k3 >> 10) - (k1 >> 10);
            int j1 = k1 & 1023;
            float Srow = __shfl(Sloc[mt], quad * 4 + r, 64);   // S of row quad*4+r
            int mq = (int)(Srow * 2.002f) + 5;                 // per-row hard margin
            jd[mt][r] = (g21 > mq) ? j1 : -1;
            if (m16 == 0) {
                int rowG = wrow0 + mt * 16 + quad * 4 + r;
                if (g21 > mq) {
                    out[IDXOFF + rowG] = (float)j1;
                } else if (g31 > mq) {                         // winner in {j1, j2}
                    int p = atomicAdd(&sCnt[0], 1);
                    sPairRow[p] = rowG; sPairJJ[p] = j1 | ((k2 & 1023) << 10);
                } else {                                       // rare: full rescan
                    int p = atomicAdd(&sCnt[1], 1);
                    sFullRow[p] = rowG;
                }
            }
        }

    // q_st + loss for decided rows, coalesced: lane = dim; winner broadcast via static shfl
    float part = 0.f;
    #pragma unroll
    for (int i = 0; i < 32; ++i) {      // row i = mt(i>>4)*16 + quad((i&15)>>2)*4 + r(i&3)
        int jr = __shfl(jd[i >> 4][i & 3], ((i & 15) >> 2) * 16, 64);
        if (jr >= 0) {
            #pragma clang fp contract(off)
            int rowG = wrow0 + i;
            float xv = x[rowG * 64 + lane];
            float wv = w[jr * 64 + lane];
            float diff = wv - xv;
            part += diff * diff;
            out[QOFF + rowG * 64 + lane] = xv + diff;
        }
    }
    for (int off = 32; off > 0; off >>= 1) part += __shfl_down(part, off, 64);
    if (lane == 0) sPart[wave] = part;
    __syncthreads();                    // sPart + LDS lists + sCnt final
    if (tid == 0) {
        partial[blockIdx.x] = (sPart[0] + sPart[1]) + (sPart[2] + sPart[3]);
        int np_ = sCnt[0], nf = sCnt[1];
        sBase[0] = np_ ? atomicAdd(&gcnt[0], np_) : 0;     // one atomic per block/category
        sBase[1] = nf  ? atomicAdd(&gcnt[1], nf)  : 0;
    }
    __syncthreads();                    // sBase ready
    if (tid < sCnt[0]) {
        int d = sBase[0] + tid;
        pairRows[d] = sPairRow[tid]; pairJJ[d] = sPairJJ[tid];
    }
    if (tid < sCnt[1]) fullRows[sBase[1] + tid] = sFullRow[tid];
}

// ---------- finish: dense lists; exact pair-compares (thread) + coalesced full rescans ----
__global__ __launch_bounds__(256) void vq_finish(
    const float* __restrict__ x, const float* __restrict__ w, const float* __restrict__ wT,
    const float* __restrict__ se, float* __restrict__ out, float* __restrict__ partial,
    const int* __restrict__ gcnt, const int* __restrict__ pairRows,
    const int* __restrict__ pairJJ, const int* __restrict__ fullRows) {
    __shared__ float sPart[4];
    const int tid = threadIdx.x;
    const int lane = tid & 63, wave = tid >> 6;
    const int nPair = gcnt[0], nFull = gcnt[1];
    const int gthread = blockIdx.x * 256 + tid, nThreads = gridDim.x * 256;
    const int gwave = blockIdx.x * 4 + wave,   nWaves = gridDim.x * 4;
    float part = 0.f;

    // Phase A: winner in {ja, jb}; exact compare with np first-index tie rule
    for (int i = gthread; i < nPair; i += nThreads) {
        int row = pairRows[i], jj = pairJJ[i];
        int ja = jj & 1023, jb = (jj >> 10) & 1023;
        if (ja > jb) { int t = ja; ja = jb; jb = t; }
        float xr[64];
        const f32x4* xp = (const f32x4*)(x + row * 64);
        #pragma unroll
        for (int t = 0; t < 16; ++t) {
            f32x4 v = xp[t];
            xr[4 * t] = v[0]; xr[4 * t + 1] = v[1]; xr[4 * t + 2] = v[2]; xr[4 * t + 3] = v[3];
        }
        float cr = np_norm64(xr);
        float da = exact_d(cr, se[ja], exact_dot64(xr, w + ja * 64));
        float db = exact_d(cr, se[jb], exact_dot64(xr, w + jb * 64));
        int win = (db < da) ? jb : ja;
        out[IDXOFF + row] = (float)win;
        const float* e = w + win * 64;
        {
            #pragma clang fp contract(off)
            #pragma unroll
            for (int i2 = 0; i2 < 64; ++i2) {
                float diff = e[i2] - xr[i2];
                part += diff * diff;
                out[QOFF + row * 64 + i2] = xr[i2] + diff;
            }
        }
    }

    // Phase B: full exact rescan, one row per wave.  Coalesced: lane owns 4 consecutive
    // codes per pass (f32x4 over codes from wT), dims iterate outer; the 4-stripe
    // accumulator order (q = i&3, dims ascending) is bit-identical to exact_dot64.
    const f32x4* wT4 = (const f32x4*)wT;
    for (int i = gwave; i < nFull; i += nWaves) {
        int row = fullRows[i];
        float xr[64];                                    // same row for all lanes (broadcast)
        const f32x4* xp = (const f32x4*)(x + row * 64);
        #pragma unroll
        for (int t = 0; t < 16; ++t) {
            f32x4 v = xp[t];
            xr[4 * t] = v[0]; xr[4 * t + 1] = v[1]; xr[4 * t + 2] = v[2]; xr[4 * t + 3] = v[3];
        }
        float cr = np_norm64(xr);
        float bd = 3.402823466e38f; int bj = 0;
        #pragma unroll
        for (int g = 0; g < 4; ++g) {                    // pass g: codes g*256 + 4*lane + c
            f32x4 a0 = {0.f,0.f,0.f,0.f}, a1 = a0, a2 = a0, a3 = a0;
            #pragma unroll 4
            for (int i2 = 0; i2 < 64; i2 += 4) {
                f32x4 w0 = wT4[(i2 + 0) * 256 + g * 64 + lane];
                f32x4 w1 = wT4[(i2 + 1) * 256 + g * 64 + lane];
                f32x4 w2 = wT4[(i2 + 2) * 256 + g * 64 + lane];
                f32x4 w3 = wT4[(i2 + 3) * 256 + g * 64 + lane];
                #pragma unroll
                for (int c = 0; c < 4; ++c) {
                    a0[c] = fmaf(xr[i2 + 0], w0[c], a0[c]);
                    a1[c] = fmaf(xr[i2 + 1], w1[c], a1[c]);
                    a2[c] = fmaf(xr[i2 + 2], w2[c], a2[c]);
                    a3[c] = fmaf(xr[i2 + 3], w3[c], a3[c]);
                }
            }
            #pragma unroll
            for (int c = 0; c < 4; ++c) {
                float dot = (a0[c] + a1[c]) + (a2[c] + a3[c]);
                int j = g * 256 + lane * 4 + c;
                float d = exact_d(cr, se[j], dot);
                if (d < bd) { bd = d; bj = j; }          // per-lane j ascending => np tie rule
            }
        }
        for (int mask = 1; mask < 64; mask <<= 1) {
            float od = __shfl_xor(bd, mask, 64);
            int   oj = __shfl_xor(bj, mask, 64);
            if (od < bd || (od == bd && oj < bj)) { bd = od; bj = oj; }
        }
        {
            #pragma clang fp contract(off)
            float xv = x[row * 64 + lane];
            float wv = w[bj * 64 + lane];
            float diff = wv - xv;
            part += diff * diff;
            out[QOFF + row * 64 + lane] = xv + diff;
        }
        if (lane == 0) out[IDXOFF + row] = (float)bj;
    }

    for (int off = 32; off > 0; off >>= 1) part += __shfl_down(part, off, 64);
    if (lane == 0) sPart[wave] = part;
    __syncthreads();
    if (tid == 0) partial[NSCR + blockIdx.x] = (sPart[0] + sPart[1]) + (sPart[2] + sPart[3]);
}

// ---------- loss: single block sums the 1536 per-block partials, one writer ----------
__global__ __launch_bounds__(256) void vq_loss(const float* __restrict__ partial,
                                               float* __restrict__ out) {
    __shared__ float red[4];
    const int tid = threadIdx.x, lane = tid & 63, wave = tid >> 6;
    float s = 0.f;
    #pragma unroll
    for (int t = 0; t < 6; ++t) s += partial[t * 256 + tid];   // 6*256 = 1536 = NSCR+NFIN
    for (int off = 32; off > 0; off >>= 1) s += __shfl_down(s, off, 64);
    if (lane == 0) red[wave] = s;
    __syncthreads();
    if (tid == 0) out[0] = ((red[0] + red[1]) + (red[2] + red[3])) * (1.25f / 8388608.0f);
}

extern "C" void kernel_launch(void* const* d_in, const int* in_sizes, int n_in,
                              void* d_out, int out_size, void* d_ws, size_t ws_size,
                              hipStream_t stream) {
    const float* x = (const float*)d_in[0];
    const float* w = (const float*)d_in[1];
    float* out = (float*)d_out;

    unsigned short* Gf = (unsigned short*)d_ws;                  // 128 KB fragment-order fp16
    float* se   = (float*)((char*)d_ws + 131072);                // 4 KB
    float* se20 = (float*)((char*)d_ws + 135168);                // 4 KB
    float* wT   = (float*)((char*)d_ws + 139264);                // 256 KB column-major fp32
    int* gcnt   = (int*)((char*)d_ws + 401408);                  // 8 B (pad to 512)
    int* pairRows = (int*)((char*)d_ws + 401920);                // 512 KB worst case
    int* pairJJ   = pairRows + NROWS;                            // 512 KB
    int* fullRows = pairJJ + NROWS;                              // 512 KB
    float* partial = (float*)(fullRows + NROWS);                 // 6 KB (1536 floats)

    vq_prep<<<32, 256, 0, stream>>>(w, Gf, wT, se, se20, gcnt);
    vq_screen<<<NSCR, 256, 0, stream>>>(x, w, Gf, se20, out, partial, gcnt,
                                        pairRows, pairJJ, fullRows);
    vq_finish<<<NFIN, 256, 0, stream>>>(x, w, wT, se, out, partial, gcnt,
                                        pairRows, pairJJ, fullRows);
    vq_loss<<<1, 256, 0, stream>>>(partial, out);
}